// Round 1
// baseline (5534.233 us; speedup 1.0000x reference)
//
#include <hip/hip_runtime.h>

#define N_NODES 50000
#define D 128
#define HALF 64
#define E_EDGES 625000

__global__ void zero_kernel(float* __restrict__ p, int n) {
    int i = blockIdx.x * blockDim.x + threadIdx.x;
    int stride = gridDim.x * blockDim.x;
    for (; i < n; i += stride) p[i] = 0.0f;
}

// One 32-lane group per edge: gather x[src] (128 f32 = 32 lanes x float4),
// scatter-add into msum[dst]. Optionally count in-degree (lane 0).
__global__ void aggregate_kernel(const float* __restrict__ x, const int* __restrict__ ei,
                                 float* __restrict__ msum, float* __restrict__ cnt) {
    int gid = blockIdx.x * blockDim.x + threadIdx.x;
    int e = gid >> 5;
    int lane = gid & 31;
    if (e >= E_EDGES) return;
    int src = ei[e];
    int dst = ei[E_EDGES + e];
    const float4 v = *reinterpret_cast<const float4*>(x + (size_t)src * D + lane * 4);
    float* base = msum + (size_t)dst * D + lane * 4;
    atomicAdd(base + 0, v.x);
    atomicAdd(base + 1, v.y);
    atomicAdd(base + 2, v.z);
    atomicAdd(base + 3, v.w);
    if (cnt != nullptr && lane == 0) atomicAdd(cnt + dst, 1.0f);
}

// One wave (64 lanes) per node. Lane c computes h_in[c] and h_out[c].
// h layout: [N][128] = [h_in (64) | h_out (64)]  (matches concat order x,h_in,h_out later)
__global__ void conv_kernel(const float* __restrict__ x,
                            const float* __restrict__ msum_in, const float* __restrict__ cnt_in,
                            const float* __restrict__ msum_out, const float* __restrict__ cnt_out,
                            const float* __restrict__ Wl_in, const float* __restrict__ bl_in,
                            const float* __restrict__ Wr_in,
                            const float* __restrict__ Wl_out, const float* __restrict__ bl_out,
                            const float* __restrict__ Wr_out,
                            float* __restrict__ h) {
    int gid = blockIdx.x * blockDim.x + threadIdx.x;
    int node = gid >> 6;
    int lane = gid & 63;
    if (node >= N_NODES) return;
    size_t base = (size_t)node * D;
    float inv_in = 1.0f / fmaxf(cnt_in[node], 1.0f);
    float inv_out = 1.0f / fmaxf(cnt_out[node], 1.0f);
    float acc_in = bl_in[lane];
    float acc_out = bl_out[lane];
#pragma unroll 8
    for (int k = 0; k < D; ++k) {
        float xk = x[base + k];               // wave-uniform -> scalar load
        float mi = msum_in[base + k] * inv_in;
        float mo = msum_out[base + k] * inv_out;
        int w = k * HALF + lane;              // coalesced weight columns
        acc_in  += mi * Wl_in[w] + xk * Wr_in[w];
        acc_out += mo * Wl_out[w] + xk * Wr_out[w];
    }
    h[base + lane] = fmaxf(acc_in, 0.0f);
    h[base + HALF + lane] = fmaxf(acc_out, 0.0f);
}

// x_new = relu([x | h] @ W + b), W is [256][128]. One wave per node,
// lane owns output cols (lane) and (lane+64).
__global__ void combine_kernel(const float* __restrict__ x, const float* __restrict__ h,
                               const float* __restrict__ W, const float* __restrict__ b,
                               float* __restrict__ xout) {
    int gid = blockIdx.x * blockDim.x + threadIdx.x;
    int node = gid >> 6;
    int lane = gid & 63;
    if (node >= N_NODES) return;
    size_t base = (size_t)node * D;
    float acc0 = b[lane];
    float acc1 = b[HALF + lane];
#pragma unroll 8
    for (int k = 0; k < D; ++k) {
        float v = x[base + k];                // uniform -> scalar
        acc0 += v * W[k * D + lane];
        acc1 += v * W[k * D + HALF + lane];
    }
#pragma unroll 8
    for (int k = 0; k < D; ++k) {
        float v = h[base + k];
        acc0 += v * W[(D + k) * D + lane];
        acc1 += v * W[(D + k) * D + HALF + lane];
    }
    xout[base + lane] = fmaxf(acc0, 0.0f);
    xout[base + HALF + lane] = fmaxf(acc1, 0.0f);
}

// out[node] = dot(x[node], fW) + fb. One wave per node, butterfly reduce.
__global__ void final_kernel(const float* __restrict__ x, const float* __restrict__ fW,
                             const float* __restrict__ fb, float* __restrict__ out) {
    int gid = blockIdx.x * blockDim.x + threadIdx.x;
    int node = gid >> 6;
    int lane = gid & 63;
    if (node >= N_NODES) return;
    size_t base = (size_t)node * D;
    float v = x[base + lane] * fW[lane] + x[base + HALF + lane] * fW[HALF + lane];
#pragma unroll
    for (int off = 32; off > 0; off >>= 1) v += __shfl_xor(v, off, 64);
    if (lane == 0) out[node] = v + fb[0];
}

extern "C" void kernel_launch(void* const* d_in, const int* in_sizes, int n_in,
                              void* d_out, int out_size, void* d_ws, size_t ws_size,
                              hipStream_t stream) {
    const float* x       = (const float*)d_in[0];
    const int*   ei_in   = (const int*)d_in[1];
    const int*   ei_out  = (const int*)d_in[2];
    const float* in_Wl0  = (const float*)d_in[3];
    const float* in_bl0  = (const float*)d_in[4];
    const float* in_Wr0  = (const float*)d_in[5];
    const float* out_Wl0 = (const float*)d_in[6];
    const float* out_bl0 = (const float*)d_in[7];
    const float* out_Wr0 = (const float*)d_in[8];
    const float* comb_W0 = (const float*)d_in[9];
    const float* comb_b0 = (const float*)d_in[10];
    const float* in_Wl1  = (const float*)d_in[11];
    const float* in_bl1  = (const float*)d_in[12];
    const float* in_Wr1  = (const float*)d_in[13];
    const float* out_Wl1 = (const float*)d_in[14];
    const float* out_bl1 = (const float*)d_in[15];
    const float* out_Wr1 = (const float*)d_in[16];
    const float* comb_W1 = (const float*)d_in[17];
    const float* comb_b1 = (const float*)d_in[18];
    const float* final_W = (const float*)d_in[19];
    const float* final_b = (const float*)d_in[20];
    float* out = (float*)d_out;

    float* ws = (float*)d_ws;
    const size_t nd = (size_t)N_NODES * D;
    float* A    = ws;            // msum_in, later reused as X2
    float* B    = A + nd;        // msum_out
    float* H    = B + nd;        // [h_in | h_out]
    float* X1   = H + nd;        // layer-0 output
    float* cin  = X1 + nd;       // in-degree counts (float)
    float* cout_ = cin + N_NODES;

    const dim3 blk(256);
    const int agg_grid  = (E_EDGES * 32) / 256;      // 78125, exact
    const int node_grid = (N_NODES * 64) / 256;      // 12500, exact

    // ---- layer 0 ----
    zero_kernel<<<2048, blk, 0, stream>>>(A, (int)(2 * nd));
    zero_kernel<<<64, blk, 0, stream>>>(cin, 2 * N_NODES);
    aggregate_kernel<<<agg_grid, blk, 0, stream>>>(x, ei_in, A, cin);
    aggregate_kernel<<<agg_grid, blk, 0, stream>>>(x, ei_out, B, cout_);
    conv_kernel<<<node_grid, blk, 0, stream>>>(x, A, cin, B, cout_,
                                               in_Wl0, in_bl0, in_Wr0,
                                               out_Wl0, out_bl0, out_Wr0, H);
    combine_kernel<<<node_grid, blk, 0, stream>>>(x, H, comb_W0, comb_b0, X1);

    // ---- layer 1 (counts are identical; reuse cin/cout_) ----
    zero_kernel<<<2048, blk, 0, stream>>>(A, (int)(2 * nd));
    aggregate_kernel<<<agg_grid, blk, 0, stream>>>(X1, ei_in, A, nullptr);
    aggregate_kernel<<<agg_grid, blk, 0, stream>>>(X1, ei_out, B, nullptr);
    conv_kernel<<<node_grid, blk, 0, stream>>>(X1, A, cin, B, cout_,
                                               in_Wl1, in_bl1, in_Wr1,
                                               out_Wl1, out_bl1, out_Wr1, H);
    combine_kernel<<<node_grid, blk, 0, stream>>>(X1, H, comb_W1, comb_b1, A); // A = X2

    // ---- final ----
    final_kernel<<<node_grid, blk, 0, stream>>>(A, final_W, final_b, out);
}

// Round 2
// 1659.322 us; speedup vs baseline: 3.3352x; 3.3352x over previous
//
#include <hip/hip_runtime.h>

#define N_NODES 50000
#define D 128
#define HALF 64
#define E_EDGES 625000

__global__ void zero_int_kernel(int* __restrict__ p, int n) {
    int i = blockIdx.x * blockDim.x + threadIdx.x;
    int stride = gridDim.x * blockDim.x;
    for (; i < n; i += stride) p[i] = 0;
}

// Histogram of destination nodes (int atomics - cheap).
__global__ void hist_kernel(const int* __restrict__ ei, int* __restrict__ deg) {
    int e = blockIdx.x * blockDim.x + threadIdx.x;
    if (e >= E_EDGES) return;
    atomicAdd(&deg[ei[E_EDGES + e]], 1);
}

// Single-block exclusive scan of deg[n] -> rowptr[n] (and rowptr[n]=total).
// Also writes the exclusive prefix into cursor (in-place over deg is safe:
// each index is read then written by the same thread).
__global__ void scan_kernel(int* __restrict__ deg_cursor, int* __restrict__ rowptr, int n) {
    __shared__ int temp[1024];
    __shared__ int carry;
    if (threadIdx.x == 0) carry = 0;
    __syncthreads();
    for (int base = 0; base < n; base += 1024) {
        int i = base + threadIdx.x;
        int v = (i < n) ? deg_cursor[i] : 0;
        temp[threadIdx.x] = v;
        __syncthreads();
        for (int off = 1; off < 1024; off <<= 1) {
            int t = (threadIdx.x >= off) ? temp[threadIdx.x - off] : 0;
            __syncthreads();
            temp[threadIdx.x] += t;
            __syncthreads();
        }
        if (i < n) {
            int excl = carry + temp[threadIdx.x] - v;
            rowptr[i] = excl;
            deg_cursor[i] = excl;   // cursor for csr_build
        }
        int total = temp[1023];
        __syncthreads();
        if (threadIdx.x == 0) carry += total;
        __syncthreads();
    }
    if (threadIdx.x == 0) rowptr[n] = carry;
}

// Scatter edges into CSR adjacency (by destination): csr[pos] = src.
__global__ void csr_build_kernel(const int* __restrict__ ei, int* __restrict__ cursor,
                                 int* __restrict__ csr) {
    int e = blockIdx.x * blockDim.x + threadIdx.x;
    if (e >= E_EDGES) return;
    int src = ei[e];
    int dst = ei[E_EDGES + e];
    int pos = atomicAdd(&cursor[dst], 1);
    csr[pos] = src;
}

// One wave per node: pull-sum x[src] over the node's CSR row, write the MEAN.
// Lane holds dims (2*lane, 2*lane+1): one coalesced 512B wave-read per edge.
__global__ void pull_mean_kernel(const float* __restrict__ x, const int* __restrict__ rowptr,
                                 const int* __restrict__ csr, float* __restrict__ mean) {
    int gid = blockIdx.x * blockDim.x + threadIdx.x;
    int node = gid >> 6;
    int lane = gid & 63;
    if (node >= N_NODES) return;
    int r0 = rowptr[node], r1 = rowptr[node + 1];
    float2 acc = make_float2(0.0f, 0.0f);
    int j = r0;
    for (; j + 2 <= r1; j += 2) {                    // 2 loads in flight
        int s0 = csr[j], s1 = csr[j + 1];
        const float2 v0 = *reinterpret_cast<const float2*>(x + (size_t)s0 * D + lane * 2);
        const float2 v1 = *reinterpret_cast<const float2*>(x + (size_t)s1 * D + lane * 2);
        acc.x += v0.x + v1.x;
        acc.y += v0.y + v1.y;
    }
    if (j < r1) {
        int s0 = csr[j];
        const float2 v0 = *reinterpret_cast<const float2*>(x + (size_t)s0 * D + lane * 2);
        acc.x += v0.x;
        acc.y += v0.y;
    }
    float inv = 1.0f / fmaxf((float)(r1 - r0), 1.0f);
    float2 m = make_float2(acc.x * inv, acc.y * inv);
    *reinterpret_cast<float2*>(mean + (size_t)node * D + lane * 2) = m;
}

// One wave (64 lanes) per node. Lane c computes h_in[c] and h_out[c].
// h layout: [N][128] = [h_in (64) | h_out (64)]
__global__ void conv_kernel(const float* __restrict__ x,
                            const float* __restrict__ mean_in, const float* __restrict__ mean_out,
                            const float* __restrict__ Wl_in, const float* __restrict__ bl_in,
                            const float* __restrict__ Wr_in,
                            const float* __restrict__ Wl_out, const float* __restrict__ bl_out,
                            const float* __restrict__ Wr_out,
                            float* __restrict__ h) {
    int gid = blockIdx.x * blockDim.x + threadIdx.x;
    int node = gid >> 6;
    int lane = gid & 63;
    if (node >= N_NODES) return;
    size_t base = (size_t)node * D;
    float acc_in = bl_in[lane];
    float acc_out = bl_out[lane];
#pragma unroll 8
    for (int k = 0; k < D; ++k) {
        float xk = x[base + k];               // wave-uniform -> scalar load
        float mi = mean_in[base + k];
        float mo = mean_out[base + k];
        int w = k * HALF + lane;              // coalesced weight columns
        acc_in  += mi * Wl_in[w] + xk * Wr_in[w];
        acc_out += mo * Wl_out[w] + xk * Wr_out[w];
    }
    h[base + lane] = fmaxf(acc_in, 0.0f);
    h[base + HALF + lane] = fmaxf(acc_out, 0.0f);
}

// x_new = relu([x | h] @ W + b), W is [256][128]. One wave per node,
// lane owns output cols (lane) and (lane+64).
__global__ void combine_kernel(const float* __restrict__ x, const float* __restrict__ h,
                               const float* __restrict__ W, const float* __restrict__ b,
                               float* __restrict__ xout) {
    int gid = blockIdx.x * blockDim.x + threadIdx.x;
    int node = gid >> 6;
    int lane = gid & 63;
    if (node >= N_NODES) return;
    size_t base = (size_t)node * D;
    float acc0 = b[lane];
    float acc1 = b[HALF + lane];
#pragma unroll 8
    for (int k = 0; k < D; ++k) {
        float v = x[base + k];                // uniform -> scalar
        acc0 += v * W[k * D + lane];
        acc1 += v * W[k * D + HALF + lane];
    }
#pragma unroll 8
    for (int k = 0; k < D; ++k) {
        float v = h[base + k];
        acc0 += v * W[(D + k) * D + lane];
        acc1 += v * W[(D + k) * D + HALF + lane];
    }
    xout[base + lane] = fmaxf(acc0, 0.0f);
    xout[base + HALF + lane] = fmaxf(acc1, 0.0f);
}

// out[node] = dot(x[node], fW) + fb. One wave per node, butterfly reduce.
__global__ void final_kernel(const float* __restrict__ x, const float* __restrict__ fW,
                             const float* __restrict__ fb, float* __restrict__ out) {
    int gid = blockIdx.x * blockDim.x + threadIdx.x;
    int node = gid >> 6;
    int lane = gid & 63;
    if (node >= N_NODES) return;
    size_t base = (size_t)node * D;
    float v = x[base + lane] * fW[lane] + x[base + HALF + lane] * fW[HALF + lane];
#pragma unroll
    for (int off = 32; off > 0; off >>= 1) v += __shfl_xor(v, off, 64);
    if (lane == 0) out[node] = v + fb[0];
}

extern "C" void kernel_launch(void* const* d_in, const int* in_sizes, int n_in,
                              void* d_out, int out_size, void* d_ws, size_t ws_size,
                              hipStream_t stream) {
    const float* x       = (const float*)d_in[0];
    const int*   ei_in   = (const int*)d_in[1];
    const int*   ei_out  = (const int*)d_in[2];
    const float* in_Wl0  = (const float*)d_in[3];
    const float* in_bl0  = (const float*)d_in[4];
    const float* in_Wr0  = (const float*)d_in[5];
    const float* out_Wl0 = (const float*)d_in[6];
    const float* out_bl0 = (const float*)d_in[7];
    const float* out_Wr0 = (const float*)d_in[8];
    const float* comb_W0 = (const float*)d_in[9];
    const float* comb_b0 = (const float*)d_in[10];
    const float* in_Wl1  = (const float*)d_in[11];
    const float* in_bl1  = (const float*)d_in[12];
    const float* in_Wr1  = (const float*)d_in[13];
    const float* out_Wl1 = (const float*)d_in[14];
    const float* out_bl1 = (const float*)d_in[15];
    const float* out_Wr1 = (const float*)d_in[16];
    const float* comb_W1 = (const float*)d_in[17];
    const float* comb_b1 = (const float*)d_in[18];
    const float* final_W = (const float*)d_in[19];
    const float* final_b = (const float*)d_in[20];
    float* out = (float*)d_out;

    const size_t nd = (size_t)N_NODES * D;
    float* ws   = (float*)d_ws;
    float* A    = ws;            // mean_in, later reused as X2
    float* B    = A + nd;        // mean_out
    float* H    = B + nd;        // [h_in | h_out]
    float* X1   = H + nd;        // layer-0 output
    int* rp_in   = (int*)(X1 + nd);          // N+1
    int* rp_out  = rp_in + (N_NODES + 1);    // N+1
    int* cur_in  = rp_out + (N_NODES + 1);   // N (deg -> cursor)
    int* cur_out = cur_in + N_NODES;         // N
    int* csr_in  = cur_out + N_NODES;        // E
    int* csr_out = csr_in + E_EDGES;         // E

    const dim3 blk(256);
    const int edge_grid = (E_EDGES + 255) / 256;     // 2442
    const int node_grid = (N_NODES * 64) / 256;      // 12500, exact

    // ---- CSR build (once, shared by both layers) ----
    zero_int_kernel<<<64, blk, 0, stream>>>(cur_in, 2 * N_NODES);  // cur_in+cur_out contiguous
    hist_kernel<<<edge_grid, blk, 0, stream>>>(ei_in, cur_in);
    hist_kernel<<<edge_grid, blk, 0, stream>>>(ei_out, cur_out);
    scan_kernel<<<1, 1024, 0, stream>>>(cur_in, rp_in, N_NODES);
    scan_kernel<<<1, 1024, 0, stream>>>(cur_out, rp_out, N_NODES);
    csr_build_kernel<<<edge_grid, blk, 0, stream>>>(ei_in, cur_in, csr_in);
    csr_build_kernel<<<edge_grid, blk, 0, stream>>>(ei_out, cur_out, csr_out);

    // ---- layer 0 ----
    pull_mean_kernel<<<node_grid, blk, 0, stream>>>(x, rp_in, csr_in, A);
    pull_mean_kernel<<<node_grid, blk, 0, stream>>>(x, rp_out, csr_out, B);
    conv_kernel<<<node_grid, blk, 0, stream>>>(x, A, B,
                                               in_Wl0, in_bl0, in_Wr0,
                                               out_Wl0, out_bl0, out_Wr0, H);
    combine_kernel<<<node_grid, blk, 0, stream>>>(x, H, comb_W0, comb_b0, X1);

    // ---- layer 1 ----
    pull_mean_kernel<<<node_grid, blk, 0, stream>>>(X1, rp_in, csr_in, A);
    pull_mean_kernel<<<node_grid, blk, 0, stream>>>(X1, rp_out, csr_out, B);
    conv_kernel<<<node_grid, blk, 0, stream>>>(X1, A, B,
                                               in_Wl1, in_bl1, in_Wr1,
                                               out_Wl1, out_bl1, out_Wr1, H);
    combine_kernel<<<node_grid, blk, 0, stream>>>(X1, H, comb_W1, comb_b1, A); // A = X2

    // ---- final ----
    final_kernel<<<node_grid, blk, 0, stream>>>(A, final_W, final_b, out);
}

// Round 3
// 1063.819 us; speedup vs baseline: 5.2022x; 1.5598x over previous
//
#include <hip/hip_runtime.h>

#define N_NODES 50000
#define D 128
#define HALF 64
#define E_EDGES 625000
#define NPB 16   // nodes per block (4 waves x 4 nodes)
#define NPW 4    // nodes per wave

__global__ void zero_int_kernel(int* __restrict__ p, int n) {
    int i = blockIdx.x * blockDim.x + threadIdx.x;
    int stride = gridDim.x * blockDim.x;
    for (; i < n; i += stride) p[i] = 0;
}

// Histogram of destination nodes (int atomics - cheap).
__global__ void hist_kernel(const int* __restrict__ ei, int* __restrict__ deg) {
    int e = blockIdx.x * blockDim.x + threadIdx.x;
    if (e >= E_EDGES) return;
    atomicAdd(&deg[ei[E_EDGES + e]], 1);
}

// Single-block exclusive scan of deg[n] -> rowptr[n] (and rowptr[n]=total).
__global__ void scan_kernel(int* __restrict__ deg_cursor, int* __restrict__ rowptr, int n) {
    __shared__ int temp[1024];
    __shared__ int carry;
    if (threadIdx.x == 0) carry = 0;
    __syncthreads();
    for (int base = 0; base < n; base += 1024) {
        int i = base + threadIdx.x;
        int v = (i < n) ? deg_cursor[i] : 0;
        temp[threadIdx.x] = v;
        __syncthreads();
        for (int off = 1; off < 1024; off <<= 1) {
            int t = (threadIdx.x >= off) ? temp[threadIdx.x - off] : 0;
            __syncthreads();
            temp[threadIdx.x] += t;
            __syncthreads();
        }
        if (i < n) {
            int excl = carry + temp[threadIdx.x] - v;
            rowptr[i] = excl;
            deg_cursor[i] = excl;   // cursor for csr_build
        }
        int total = temp[1023];
        __syncthreads();
        if (threadIdx.x == 0) carry += total;
        __syncthreads();
    }
    if (threadIdx.x == 0) rowptr[n] = carry;
}

// Scatter edges into CSR adjacency (by destination): csr[pos] = src.
__global__ void csr_build_kernel(const int* __restrict__ ei, int* __restrict__ cursor,
                                 int* __restrict__ csr) {
    int e = blockIdx.x * blockDim.x + threadIdx.x;
    if (e >= E_EDGES) return;
    int src = ei[e];
    int dst = ei[E_EDGES + e];
    int pos = atomicAdd(&cursor[dst], 1);
    csr[pos] = src;
}

// One wave per node: pull-sum x[src] over the node's CSR row, write the MEAN.
// Lane holds dims (2*lane, 2*lane+1): one coalesced 512B wave-read per edge.
__global__ void pull_mean_kernel(const float* __restrict__ x, const int* __restrict__ rowptr,
                                 const int* __restrict__ csr, float* __restrict__ mean) {
    int gid = blockIdx.x * blockDim.x + threadIdx.x;
    int node = gid >> 6;
    int lane = gid & 63;
    if (node >= N_NODES) return;
    int r0 = rowptr[node], r1 = rowptr[node + 1];
    float2 acc = make_float2(0.0f, 0.0f);
    int j = r0;
    for (; j + 4 <= r1; j += 4) {                    // 4 loads in flight
        int s0 = csr[j], s1 = csr[j + 1], s2 = csr[j + 2], s3 = csr[j + 3];
        const float2 v0 = *reinterpret_cast<const float2*>(x + (size_t)s0 * D + lane * 2);
        const float2 v1 = *reinterpret_cast<const float2*>(x + (size_t)s1 * D + lane * 2);
        const float2 v2 = *reinterpret_cast<const float2*>(x + (size_t)s2 * D + lane * 2);
        const float2 v3 = *reinterpret_cast<const float2*>(x + (size_t)s3 * D + lane * 2);
        acc.x += v0.x + v1.x + v2.x + v3.x;
        acc.y += v0.y + v1.y + v2.y + v3.y;
    }
    for (; j < r1; ++j) {
        int s0 = csr[j];
        const float2 v0 = *reinterpret_cast<const float2*>(x + (size_t)s0 * D + lane * 2);
        acc.x += v0.x;
        acc.y += v0.y;
    }
    float inv = 1.0f / fmaxf((float)(r1 - r0), 1.0f);
    float2 m = make_float2(acc.x * inv, acc.y * inv);
    *reinterpret_cast<float2*>(mean + (size_t)node * D + lane * 2) = m;
}

// Fused SAGE layer: conv (dual-direction) -> h in LDS -> combine.
// 4 waves/block, NPW=4 nodes/wave, lane = output column.
// If final_W != nullptr: instead of writing xout rows, compute the final
// scalar dot (x2 @ final_W + final_b) and write final_out[node].
__global__ __launch_bounds__(256) void fused_layer_kernel(
    const float* __restrict__ x,
    const float* __restrict__ mean_in, const float* __restrict__ mean_out,
    const float* __restrict__ Wl_in, const float* __restrict__ bl_in,
    const float* __restrict__ Wr_in,
    const float* __restrict__ Wl_out, const float* __restrict__ bl_out,
    const float* __restrict__ Wr_out,
    const float* __restrict__ cW, const float* __restrict__ cb,
    float* __restrict__ xout,
    const float* __restrict__ final_W, const float* __restrict__ final_b,
    float* __restrict__ final_out)
{
    __shared__ float h_lds[NPB][D];   // 8 KB
    const int tid = threadIdx.x;
    const int wave = tid >> 6;
    const int lane = tid & 63;
    const int node0 = blockIdx.x * NPB + wave * NPW;   // exact: 50000 = 3125*16

    // ---- conv phase: h_in[c]=relu(mean_in@Wl_in + x@Wr_in + bl_in)[c], same for out
    float acc_in[NPW], acc_out[NPW];
    {
        const float bli = bl_in[lane], blo = bl_out[lane];
#pragma unroll
        for (int i = 0; i < NPW; ++i) { acc_in[i] = bli; acc_out[i] = blo; }
    }
    for (int k0 = 0; k0 < D; k0 += 4) {
        float wli[4], wri[4], wlo[4], wro[4];
#pragma unroll
        for (int j = 0; j < 4; ++j) {
            int w = (k0 + j) * HALF + lane;
            wli[j] = Wl_in[w]; wri[j] = Wr_in[w];
            wlo[j] = Wl_out[w]; wro[j] = Wr_out[w];
        }
#pragma unroll
        for (int i = 0; i < NPW; ++i) {
            size_t base = (size_t)(node0 + i) * D + k0;
            const float4 xi = *reinterpret_cast<const float4*>(x + base);
            const float4 mi = *reinterpret_cast<const float4*>(mean_in + base);
            const float4 mo = *reinterpret_cast<const float4*>(mean_out + base);
            acc_in[i]  += mi.x * wli[0] + mi.y * wli[1] + mi.z * wli[2] + mi.w * wli[3]
                        + xi.x * wri[0] + xi.y * wri[1] + xi.z * wri[2] + xi.w * wri[3];
            acc_out[i] += mo.x * wlo[0] + mo.y * wlo[1] + mo.z * wlo[2] + mo.w * wlo[3]
                        + xi.x * wro[0] + xi.y * wro[1] + xi.z * wro[2] + xi.w * wro[3];
        }
    }
#pragma unroll
    for (int i = 0; i < NPW; ++i) {
        h_lds[wave * NPW + i][lane]        = fmaxf(acc_in[i], 0.0f);
        h_lds[wave * NPW + i][HALF + lane] = fmaxf(acc_out[i], 0.0f);
    }
    __syncthreads();

    // ---- combine phase: x_new = relu([x | h] @ cW + cb), lane owns cols lane, lane+64
    float a0[NPW], a1[NPW];
    {
        const float cb0 = cb[lane], cb1 = cb[HALF + lane];
#pragma unroll
        for (int i = 0; i < NPW; ++i) { a0[i] = cb0; a1[i] = cb1; }
    }
    for (int k0 = 0; k0 < D; k0 += 4) {        // x part (cW rows 0..127)
        float w0[4], w1[4];
#pragma unroll
        for (int j = 0; j < 4; ++j) {
            int w = (k0 + j) * D + lane;
            w0[j] = cW[w]; w1[j] = cW[w + HALF];
        }
#pragma unroll
        for (int i = 0; i < NPW; ++i) {
            const float4 xi = *reinterpret_cast<const float4*>(x + (size_t)(node0 + i) * D + k0);
            a0[i] += xi.x * w0[0] + xi.y * w0[1] + xi.z * w0[2] + xi.w * w0[3];
            a1[i] += xi.x * w1[0] + xi.y * w1[1] + xi.z * w1[2] + xi.w * w1[3];
        }
    }
    for (int k0 = 0; k0 < D; k0 += 4) {        // h part (cW rows 128..255)
        float w0[4], w1[4];
#pragma unroll
        for (int j = 0; j < 4; ++j) {
            int w = (D + k0 + j) * D + lane;
            w0[j] = cW[w]; w1[j] = cW[w + HALF];
        }
#pragma unroll
        for (int i = 0; i < NPW; ++i) {
            const float4 hi = *reinterpret_cast<const float4*>(&h_lds[wave * NPW + i][k0]);
            a0[i] += hi.x * w0[0] + hi.y * w0[1] + hi.z * w0[2] + hi.w * w0[3];
            a1[i] += hi.x * w1[0] + hi.y * w1[1] + hi.z * w1[2] + hi.w * w1[3];
        }
    }

    if (final_W == nullptr) {
#pragma unroll
        for (int i = 0; i < NPW; ++i) {
            size_t base = (size_t)(node0 + i) * D;
            xout[base + lane]        = fmaxf(a0[i], 0.0f);
            xout[base + HALF + lane] = fmaxf(a1[i], 0.0f);
        }
    } else {
        const float fw0 = final_W[lane], fw1 = final_W[HALF + lane];
        const float fb = final_b[0];
#pragma unroll
        for (int i = 0; i < NPW; ++i) {
            float v = fmaxf(a0[i], 0.0f) * fw0 + fmaxf(a1[i], 0.0f) * fw1;
#pragma unroll
            for (int off = 32; off > 0; off >>= 1) v += __shfl_xor(v, off, 64);
            if (lane == 0) final_out[node0 + i] = v + fb;
        }
    }
}

extern "C" void kernel_launch(void* const* d_in, const int* in_sizes, int n_in,
                              void* d_out, int out_size, void* d_ws, size_t ws_size,
                              hipStream_t stream) {
    const float* x       = (const float*)d_in[0];
    const int*   ei_in   = (const int*)d_in[1];
    const int*   ei_out  = (const int*)d_in[2];
    const float* in_Wl0  = (const float*)d_in[3];
    const float* in_bl0  = (const float*)d_in[4];
    const float* in_Wr0  = (const float*)d_in[5];
    const float* out_Wl0 = (const float*)d_in[6];
    const float* out_bl0 = (const float*)d_in[7];
    const float* out_Wr0 = (const float*)d_in[8];
    const float* comb_W0 = (const float*)d_in[9];
    const float* comb_b0 = (const float*)d_in[10];
    const float* in_Wl1  = (const float*)d_in[11];
    const float* in_bl1  = (const float*)d_in[12];
    const float* in_Wr1  = (const float*)d_in[13];
    const float* out_Wl1 = (const float*)d_in[14];
    const float* out_bl1 = (const float*)d_in[15];
    const float* out_Wr1 = (const float*)d_in[16];
    const float* comb_W1 = (const float*)d_in[17];
    const float* comb_b1 = (const float*)d_in[18];
    const float* final_W = (const float*)d_in[19];
    const float* final_b = (const float*)d_in[20];
    float* out = (float*)d_out;

    const size_t nd = (size_t)N_NODES * D;
    float* ws   = (float*)d_ws;
    float* A    = ws;            // mean_in
    float* B    = A + nd;        // mean_out
    float* X1   = B + nd;        // layer-0 output
    int* rp_in   = (int*)(X1 + nd);          // N+1
    int* rp_out  = rp_in + (N_NODES + 1);    // N+1
    int* cur_in  = rp_out + (N_NODES + 1);   // N (deg -> cursor)
    int* cur_out = cur_in + N_NODES;         // N
    int* csr_in  = cur_out + N_NODES;        // E
    int* csr_out = csr_in + E_EDGES;         // E

    const dim3 blk(256);
    const int edge_grid  = (E_EDGES + 255) / 256;    // 2442
    const int node_grid  = (N_NODES * 64) / 256;     // 12500, exact
    const int fused_grid = N_NODES / NPB;            // 3125, exact

    // ---- CSR build (once, shared by both layers) ----
    zero_int_kernel<<<64, blk, 0, stream>>>(cur_in, 2 * N_NODES);  // cur_in+cur_out contiguous
    hist_kernel<<<edge_grid, blk, 0, stream>>>(ei_in, cur_in);
    hist_kernel<<<edge_grid, blk, 0, stream>>>(ei_out, cur_out);
    scan_kernel<<<1, 1024, 0, stream>>>(cur_in, rp_in, N_NODES);
    scan_kernel<<<1, 1024, 0, stream>>>(cur_out, rp_out, N_NODES);
    csr_build_kernel<<<edge_grid, blk, 0, stream>>>(ei_in, cur_in, csr_in);
    csr_build_kernel<<<edge_grid, blk, 0, stream>>>(ei_out, cur_out, csr_out);

    // ---- layer 0 ----
    pull_mean_kernel<<<node_grid, blk, 0, stream>>>(x, rp_in, csr_in, A);
    pull_mean_kernel<<<node_grid, blk, 0, stream>>>(x, rp_out, csr_out, B);
    fused_layer_kernel<<<fused_grid, blk, 0, stream>>>(
        x, A, B,
        in_Wl0, in_bl0, in_Wr0, out_Wl0, out_bl0, out_Wr0,
        comb_W0, comb_b0, X1, nullptr, nullptr, nullptr);

    // ---- layer 1 (+ fused final head) ----
    pull_mean_kernel<<<node_grid, blk, 0, stream>>>(X1, rp_in, csr_in, A);
    pull_mean_kernel<<<node_grid, blk, 0, stream>>>(X1, rp_out, csr_out, B);
    fused_layer_kernel<<<fused_grid, blk, 0, stream>>>(
        X1, A, B,
        in_Wl1, in_bl1, in_Wr1, out_Wl1, out_bl1, out_Wr1,
        comb_W1, comb_b1, nullptr, final_W, final_b, out);
}

// Round 4
// 921.054 us; speedup vs baseline: 6.0086x; 1.1550x over previous
//
#include <hip/hip_runtime.h>

#define N_NODES 50000
#define D 128
#define HALF 64
#define E_EDGES 625000
#define NPB 32   // nodes per block (4 waves x 8 nodes)
#define NPW 8    // nodes per wave

__device__ __forceinline__ int rfl(int v) { return __builtin_amdgcn_readfirstlane(v); }

__global__ void zero_int_kernel(int* __restrict__ p, int n) {
    int i = blockIdx.x * blockDim.x + threadIdx.x;
    int stride = gridDim.x * blockDim.x;
    for (; i < n; i += stride) p[i] = 0;
}

// Histogram of destination nodes for BOTH edge sets in one launch.
__global__ void hist2_kernel(const int* __restrict__ ei_in, const int* __restrict__ ei_out,
                             int* __restrict__ deg_in, int* __restrict__ deg_out) {
    int e = blockIdx.x * blockDim.x + threadIdx.x;
    if (e < E_EDGES) {
        atomicAdd(&deg_in[ei_in[E_EDGES + e]], 1);
    } else if (e < 2 * E_EDGES) {
        // idx = e - E_EDGES; dst = ei_out[E_EDGES + idx] = ei_out[e]
        atomicAdd(&deg_out[ei_out[e]], 1);
    }
}

// Exclusive scan of deg[n] -> rowptr (rowptr[n]=total), cursor = excl prefix.
// blockIdx 0 -> in arrays, blockIdx 1 -> out arrays (run both in parallel).
__global__ void scan2_kernel(int* __restrict__ cur_in, int* __restrict__ cur_out,
                             int* __restrict__ rp_in, int* __restrict__ rp_out, int n) {
    int* deg_cursor = blockIdx.x ? cur_out : cur_in;
    int* rowptr     = blockIdx.x ? rp_out  : rp_in;
    __shared__ int temp[1024];
    __shared__ int carry;
    if (threadIdx.x == 0) carry = 0;
    __syncthreads();
    for (int base = 0; base < n; base += 1024) {
        int i = base + threadIdx.x;
        int v = (i < n) ? deg_cursor[i] : 0;
        temp[threadIdx.x] = v;
        __syncthreads();
        for (int off = 1; off < 1024; off <<= 1) {
            int t = (threadIdx.x >= off) ? temp[threadIdx.x - off] : 0;
            __syncthreads();
            temp[threadIdx.x] += t;
            __syncthreads();
        }
        if (i < n) {
            int excl = carry + temp[threadIdx.x] - v;
            rowptr[i] = excl;
            deg_cursor[i] = excl;
        }
        int total = temp[1023];
        __syncthreads();
        if (threadIdx.x == 0) carry += total;
        __syncthreads();
    }
    if (threadIdx.x == 0) rowptr[n] = carry;
}

// Scatter both edge sets into CSR adjacency (by destination) in one launch.
__global__ void csr_build2_kernel(const int* __restrict__ ei_in, const int* __restrict__ ei_out,
                                  int* __restrict__ cur_in, int* __restrict__ cur_out,
                                  int* __restrict__ csr_in, int* __restrict__ csr_out) {
    int e = blockIdx.x * blockDim.x + threadIdx.x;
    if (e < E_EDGES) {
        int src = ei_in[e], dst = ei_in[E_EDGES + e];
        csr_in[atomicAdd(&cur_in[dst], 1)] = src;
    } else if (e < 2 * E_EDGES) {
        int src = ei_out[e - E_EDGES], dst = ei_out[e];
        csr_out[atomicAdd(&cur_out[dst], 1)] = src;
    }
}

// One wave per (node, direction). Scalar (SGPR) row range + CSR indices;
// masked 8-deep gather blocks keep 8 row loads in flight (clamped dups hit L1).
// Lane holds dims (2*lane, 2*lane+1): one coalesced 512B wave-read per edge.
__global__ __launch_bounds__(256) void pull_mean_dual_kernel(
    const float* __restrict__ x,
    const int* __restrict__ rp_in, const int* __restrict__ csr_in,
    const int* __restrict__ rp_out, const int* __restrict__ csr_out,
    float* __restrict__ mean_in, float* __restrict__ mean_out)
{
    int gid = blockIdx.x * blockDim.x + threadIdx.x;
    int wid = gid >> 6;
    int lane = gid & 63;
    const int* rp; const int* csr; float* mean;
    if (wid < N_NODES) { rp = rp_in; csr = csr_in; mean = mean_in; }
    else { wid -= N_NODES; rp = rp_out; csr = csr_out; mean = mean_out; }
    int node = rfl(wid);
    int r0 = rfl(rp[node]);
    int r1 = rfl(rp[node + 1]);
    float2 acc = make_float2(0.0f, 0.0f);
    for (int j = r0; j < r1; j += 8) {
        int idx[8]; float msk[8];
#pragma unroll
        for (int t = 0; t < 8; ++t) {
            int jj = j + t;
            idx[t] = csr[jj < r1 ? jj : r1 - 1];   // scalar; dup reads cache-hit
            msk[t] = (jj < r1) ? 1.0f : 0.0f;
        }
#pragma unroll
        for (int t = 0; t < 8; ++t) {
            const float2 v = *reinterpret_cast<const float2*>(x + (size_t)idx[t] * D + lane * 2);
            acc.x = fmaf(msk[t], v.x, acc.x);
            acc.y = fmaf(msk[t], v.y, acc.y);
        }
    }
    float inv = 1.0f / fmaxf((float)(r1 - r0), 1.0f);
    *reinterpret_cast<float2*>(mean + (size_t)node * D + lane * 2) =
        make_float2(acc.x * inv, acc.y * inv);
}

// Fused SAGE layer: dual-direction conv -> h in wave-private LDS -> combine.
// 4 waves/block, NPW=8 nodes/wave, lane = output column. Node ids / row
// offsets are readfirstlane'd so input rows load via scalar pipe (broadcast)
// and the vector pipe does (almost) pure FMA.
__global__ __launch_bounds__(256) void fused_layer_kernel(
    const float* __restrict__ x,
    const float* __restrict__ mean_in, const float* __restrict__ mean_out,
    const float* __restrict__ Wl_in, const float* __restrict__ bl_in,
    const float* __restrict__ Wr_in,
    const float* __restrict__ Wl_out, const float* __restrict__ bl_out,
    const float* __restrict__ Wr_out,
    const float* __restrict__ cW, const float* __restrict__ cb,
    float* __restrict__ xout,
    const float* __restrict__ final_W, const float* __restrict__ final_b,
    float* __restrict__ final_out)
{
    __shared__ float h_lds[NPB][D];   // 16 KB, wave-private regions
    const int tid = threadIdx.x;
    const int wave = tid >> 6;
    const int lane = tid & 63;
    const int node0 = rfl(blockIdx.x * NPB + wave * NPW);

    int obase[NPW];   // scalar row offsets (clamped for tail block)
#pragma unroll
    for (int i = 0; i < NPW; ++i) {
        int nn = node0 + i; if (nn > N_NODES - 1) nn = N_NODES - 1;
        obase[i] = nn * D;
    }

    // ---- conv phase ----
    float acc_in[NPW], acc_out[NPW];
    {
        const float bli = bl_in[lane], blo = bl_out[lane];
#pragma unroll
        for (int i = 0; i < NPW; ++i) { acc_in[i] = bli; acc_out[i] = blo; }
    }
    for (int k0 = 0; k0 < D; k0 += 4) {
        float wli[4], wri[4], wlo[4], wro[4];
#pragma unroll
        for (int j = 0; j < 4; ++j) {
            int w = (k0 + j) * HALF + lane;
            wli[j] = Wl_in[w]; wri[j] = Wr_in[w];
            wlo[j] = Wl_out[w]; wro[j] = Wr_out[w];
        }
#pragma unroll
        for (int i = 0; i < NPW; ++i) {
            const float4 xi = *reinterpret_cast<const float4*>(x + obase[i] + k0);
            const float4 mi = *reinterpret_cast<const float4*>(mean_in + obase[i] + k0);
            const float4 mo = *reinterpret_cast<const float4*>(mean_out + obase[i] + k0);
            acc_in[i]  = fmaf(mi.x, wli[0], fmaf(mi.y, wli[1], fmaf(mi.z, wli[2], fmaf(mi.w, wli[3], acc_in[i]))));
            acc_in[i]  = fmaf(xi.x, wri[0], fmaf(xi.y, wri[1], fmaf(xi.z, wri[2], fmaf(xi.w, wri[3], acc_in[i]))));
            acc_out[i] = fmaf(mo.x, wlo[0], fmaf(mo.y, wlo[1], fmaf(mo.z, wlo[2], fmaf(mo.w, wlo[3], acc_out[i]))));
            acc_out[i] = fmaf(xi.x, wro[0], fmaf(xi.y, wro[1], fmaf(xi.z, wro[2], fmaf(xi.w, wro[3], acc_out[i]))));
        }
    }
#pragma unroll
    for (int i = 0; i < NPW; ++i) {
        h_lds[wave * NPW + i][lane]        = fmaxf(acc_in[i], 0.0f);
        h_lds[wave * NPW + i][HALF + lane] = fmaxf(acc_out[i], 0.0f);
    }
    // no __syncthreads: each wave reads only its own h_lds rows

    // ---- combine phase ----
    float a0[NPW], a1[NPW];
    {
        const float cb0 = cb[lane], cb1 = cb[HALF + lane];
#pragma unroll
        for (int i = 0; i < NPW; ++i) { a0[i] = cb0; a1[i] = cb1; }
    }
    for (int k0 = 0; k0 < D; k0 += 4) {        // x part (cW rows 0..127)
        float w0[4], w1[4];
#pragma unroll
        for (int j = 0; j < 4; ++j) {
            int w = (k0 + j) * D + lane;
            w0[j] = cW[w]; w1[j] = cW[w + HALF];
        }
#pragma unroll
        for (int i = 0; i < NPW; ++i) {
            const float4 xi = *reinterpret_cast<const float4*>(x + obase[i] + k0);
            a0[i] = fmaf(xi.x, w0[0], fmaf(xi.y, w0[1], fmaf(xi.z, w0[2], fmaf(xi.w, w0[3], a0[i]))));
            a1[i] = fmaf(xi.x, w1[0], fmaf(xi.y, w1[1], fmaf(xi.z, w1[2], fmaf(xi.w, w1[3], a1[i]))));
        }
    }
    for (int k0 = 0; k0 < D; k0 += 4) {        // h part (cW rows 128..255)
        float w0[4], w1[4];
#pragma unroll
        for (int j = 0; j < 4; ++j) {
            int w = (D + k0 + j) * D + lane;
            w0[j] = cW[w]; w1[j] = cW[w + HALF];
        }
#pragma unroll
        for (int i = 0; i < NPW; ++i) {
            const float4 hi = *reinterpret_cast<const float4*>(&h_lds[wave * NPW + i][k0]);
            a0[i] = fmaf(hi.x, w0[0], fmaf(hi.y, w0[1], fmaf(hi.z, w0[2], fmaf(hi.w, w0[3], a0[i]))));
            a1[i] = fmaf(hi.x, w1[0], fmaf(hi.y, w1[1], fmaf(hi.z, w1[2], fmaf(hi.w, w1[3], a1[i]))));
        }
    }

    if (final_W == nullptr) {
#pragma unroll
        for (int i = 0; i < NPW; ++i) {
            if (node0 + i < N_NODES) {
                xout[obase[i] + lane]        = fmaxf(a0[i], 0.0f);
                xout[obase[i] + HALF + lane] = fmaxf(a1[i], 0.0f);
            }
        }
    } else {
        const float fw0 = final_W[lane], fw1 = final_W[HALF + lane];
        const float fb = final_b[0];
#pragma unroll
        for (int i = 0; i < NPW; ++i) {
            float v = fmaxf(a0[i], 0.0f) * fw0 + fmaxf(a1[i], 0.0f) * fw1;
#pragma unroll
            for (int off = 32; off > 0; off >>= 1) v += __shfl_xor(v, off, 64);
            if (lane == 0 && node0 + i < N_NODES) final_out[node0 + i] = v + fb;
        }
    }
}

extern "C" void kernel_launch(void* const* d_in, const int* in_sizes, int n_in,
                              void* d_out, int out_size, void* d_ws, size_t ws_size,
                              hipStream_t stream) {
    const float* x       = (const float*)d_in[0];
    const int*   ei_in   = (const int*)d_in[1];
    const int*   ei_out  = (const int*)d_in[2];
    const float* in_Wl0  = (const float*)d_in[3];
    const float* in_bl0  = (const float*)d_in[4];
    const float* in_Wr0  = (const float*)d_in[5];
    const float* out_Wl0 = (const float*)d_in[6];
    const float* out_bl0 = (const float*)d_in[7];
    const float* out_Wr0 = (const float*)d_in[8];
    const float* comb_W0 = (const float*)d_in[9];
    const float* comb_b0 = (const float*)d_in[10];
    const float* in_Wl1  = (const float*)d_in[11];
    const float* in_bl1  = (const float*)d_in[12];
    const float* in_Wr1  = (const float*)d_in[13];
    const float* out_Wl1 = (const float*)d_in[14];
    const float* out_bl1 = (const float*)d_in[15];
    const float* out_Wr1 = (const float*)d_in[16];
    const float* comb_W1 = (const float*)d_in[17];
    const float* comb_b1 = (const float*)d_in[18];
    const float* final_W = (const float*)d_in[19];
    const float* final_b = (const float*)d_in[20];
    float* out = (float*)d_out;

    const size_t nd = (size_t)N_NODES * D;
    float* ws   = (float*)d_ws;
    float* A    = ws;            // mean_in
    float* B    = A + nd;        // mean_out
    float* X1   = B + nd;        // layer-0 output
    int* rp_in   = (int*)(X1 + nd);          // N+1
    int* rp_out  = rp_in + (N_NODES + 1);    // N+1
    int* cur_in  = rp_out + (N_NODES + 1);   // N (deg -> cursor)
    int* cur_out = cur_in + N_NODES;         // N
    int* csr_in  = cur_out + N_NODES;        // E
    int* csr_out = csr_in + E_EDGES;         // E

    const dim3 blk(256);
    const int edge2_grid = (2 * E_EDGES + 255) / 256;       // 4883
    const int pull_grid  = (2 * N_NODES * 64) / 256;        // 25000, exact
    const int fused_grid = (N_NODES + NPB - 1) / NPB;       // 1563

    // ---- CSR build (once, shared by both layers) ----
    zero_int_kernel<<<64, blk, 0, stream>>>(cur_in, 2 * N_NODES);  // cur_in+cur_out contiguous
    hist2_kernel<<<edge2_grid, blk, 0, stream>>>(ei_in, ei_out, cur_in, cur_out);
    scan2_kernel<<<2, 1024, 0, stream>>>(cur_in, cur_out, rp_in, rp_out, N_NODES);
    csr_build2_kernel<<<edge2_grid, blk, 0, stream>>>(ei_in, ei_out, cur_in, cur_out, csr_in, csr_out);

    // ---- layer 0 ----
    pull_mean_dual_kernel<<<pull_grid, blk, 0, stream>>>(x, rp_in, csr_in, rp_out, csr_out, A, B);
    fused_layer_kernel<<<fused_grid, blk, 0, stream>>>(
        x, A, B,
        in_Wl0, in_bl0, in_Wr0, out_Wl0, out_bl0, out_Wr0,
        comb_W0, comb_b0, X1, nullptr, nullptr, nullptr);

    // ---- layer 1 (+ fused final head) ----
    pull_mean_dual_kernel<<<pull_grid, blk, 0, stream>>>(X1, rp_in, csr_in, rp_out, csr_out, A, B);
    fused_layer_kernel<<<fused_grid, blk, 0, stream>>>(
        X1, A, B,
        in_Wl1, in_bl1, in_Wr1, out_Wl1, out_bl1, out_Wr1,
        comb_W1, comb_b1, nullptr, final_W, final_b, out);
}

// Round 5
// 529.058 us; speedup vs baseline: 10.4605x; 1.7409x over previous
//
#include <hip/hip_runtime.h>

#define N_NODES 50000
#define D 128
#define HALF 64
#define E_EDGES 625000
#define NPB 32   // nodes per block (4 waves x 8 nodes)
#define NPW 8    // nodes per wave

__device__ __forceinline__ int rfl(int v) { return __builtin_amdgcn_readfirstlane(v); }

__global__ void zero_int_kernel(int* __restrict__ p, int n) {
    int i = blockIdx.x * blockDim.x + threadIdx.x;
    int stride = gridDim.x * blockDim.x;
    for (; i < n; i += stride) p[i] = 0;
}

// Histogram of destination nodes for BOTH edge sets in one launch.
__global__ void hist2_kernel(const int* __restrict__ ei_in, const int* __restrict__ ei_out,
                             int* __restrict__ deg_in, int* __restrict__ deg_out) {
    int e = blockIdx.x * blockDim.x + threadIdx.x;
    if (e < E_EDGES) {
        atomicAdd(&deg_in[ei_in[E_EDGES + e]], 1);
    } else if (e < 2 * E_EDGES) {
        atomicAdd(&deg_out[ei_out[e]], 1);   // ei_out[E_EDGES + (e-E_EDGES)]
    }
}

// Shuffle-based exclusive scan: deg -> rowptr (rowptr[n]=total), cursor = excl prefix.
// blockIdx 0 -> in arrays, blockIdx 1 -> out arrays.
__global__ void scan2_kernel(int* __restrict__ cur_in, int* __restrict__ cur_out,
                             int* __restrict__ rp_in, int* __restrict__ rp_out, int n) {
    int* cur = blockIdx.x ? cur_out : cur_in;
    int* rp  = blockIdx.x ? rp_out  : rp_in;
    __shared__ int wsum[16];
    __shared__ int carry_s;
    const int tid = threadIdx.x;
    const int wave = tid >> 6;
    const int lane = tid & 63;
    if (tid == 0) carry_s = 0;
    __syncthreads();
    for (int base = 0; base < n; base += 1024) {
        int i = base + tid;
        int v = (i < n) ? cur[i] : 0;
        int s = v;                                   // inclusive wave scan
#pragma unroll
        for (int off = 1; off <= 32; off <<= 1) {
            int t = __shfl_up(s, off, 64);
            if (lane >= off) s += t;
        }
        if (lane == 63) wsum[wave] = s;
        __syncthreads();
        if (wave == 0 && lane < 16) {                // scan the 16 wave totals
            int ws = wsum[lane];
#pragma unroll
            for (int off = 1; off <= 8; off <<= 1) {
                int t = __shfl_up(ws, off, 64);
                if (lane >= off) ws += t;
            }
            wsum[lane] = ws;
        }
        __syncthreads();
        int waveoff = (wave == 0) ? 0 : wsum[wave - 1];
        int carry = carry_s;
        if (i < n) {
            int excl = carry + waveoff + s - v;
            rp[i] = excl;
            cur[i] = excl;
        }
        __syncthreads();
        if (tid == 0) carry_s = carry + wsum[15];
        __syncthreads();
    }
    if (tid == 0) rp[n] = carry_s;
}

// Scatter both edge sets into CSR adjacency (by destination) in one launch.
__global__ void csr_build2_kernel(const int* __restrict__ ei_in, const int* __restrict__ ei_out,
                                  int* __restrict__ cur_in, int* __restrict__ cur_out,
                                  int* __restrict__ csr_in, int* __restrict__ csr_out) {
    int e = blockIdx.x * blockDim.x + threadIdx.x;
    if (e < E_EDGES) {
        int src = ei_in[e], dst = ei_in[E_EDGES + e];
        csr_in[atomicAdd(&cur_in[dst], 1)] = src;
    } else if (e < 2 * E_EDGES) {
        int src = ei_out[e - E_EDGES], dst = ei_out[e];
        csr_out[atomicAdd(&cur_out[dst], 1)] = src;
    }
}

// P = X @ [Wl_a | Wl_b]  -> [N,128] (no bias; bias added post-aggregation).
// 4 waves/block, 8 nodes/wave. X rows staged wave-private into LDS (coalesced),
// consumed as uniform ds_read_b128 broadcasts.
__global__ __launch_bounds__(256) void transform_kernel(
    const float* __restrict__ X,
    const float* __restrict__ Wl_a, const float* __restrict__ Wl_b,
    float* __restrict__ P)
{
    __shared__ alignas(16) float ls[NPB][D];   // 16 KB
    const int tid = threadIdx.x;
    const int wave = tid >> 6;
    const int lane = tid & 63;
    const int node0 = rfl(blockIdx.x * NPB + wave * NPW);

    // stage this wave's 8 rows (wave-private -> no __syncthreads)
#pragma unroll
    for (int r = 0; r < 4; ++r) {
        int f = lane + 64 * r;            // 0..255 float4 slots (8 rows x 32)
        int rl = f >> 5;
        int c4 = f & 31;
        int nn = node0 + rl; if (nn > N_NODES - 1) nn = N_NODES - 1;
        *reinterpret_cast<float4*>(&ls[wave * NPW + rl][c4 * 4]) =
            *reinterpret_cast<const float4*>(X + (size_t)nn * D + c4 * 4);
    }

    float ta[NPW], tb[NPW];
#pragma unroll
    for (int i = 0; i < NPW; ++i) { ta[i] = 0.0f; tb[i] = 0.0f; }

    for (int k0 = 0; k0 < D; k0 += 4) {
        float wa[4], wb[4];
#pragma unroll
        for (int j = 0; j < 4; ++j) {
            int w = (k0 + j) * HALF + lane;
            wa[j] = Wl_a[w]; wb[j] = Wl_b[w];
        }
#pragma unroll
        for (int i = 0; i < NPW; ++i) {
            const float4 xi = *reinterpret_cast<const float4*>(&ls[wave * NPW + i][k0]);
            ta[i] = fmaf(xi.x, wa[0], fmaf(xi.y, wa[1], fmaf(xi.z, wa[2], fmaf(xi.w, wa[3], ta[i]))));
            tb[i] = fmaf(xi.x, wb[0], fmaf(xi.y, wb[1], fmaf(xi.z, wb[2], fmaf(xi.w, wb[3], tb[i]))));
        }
    }
#pragma unroll
    for (int i = 0; i < NPW; ++i) {
        int nn = node0 + i;
        if (nn < N_NODES) {
            P[(size_t)nn * D + lane]        = ta[i];
            P[(size_t)nn * D + HALF + lane] = tb[i];
        }
    }
}

// Mean-aggregate 64-wide halves of P: agg_in = mean over csr_in of P[:,0:64],
// agg_out = mean over csr_out of P[:,64:128]. One wave per (node,dir);
// 4 edges per iteration: lane = 16*sub + c4, each row gathered as 16x float4.
__global__ __launch_bounds__(256) void pull_dual_kernel(
    const float* __restrict__ P,
    const int* __restrict__ rp_in, const int* __restrict__ csr_in,
    const int* __restrict__ rp_out, const int* __restrict__ csr_out,
    float* __restrict__ agg_in, float* __restrict__ agg_out)
{
    int gid = blockIdx.x * blockDim.x + threadIdx.x;
    int wid = gid >> 6;
    const int lane = gid & 63;
    const int sub = lane >> 4;
    const int c4 = lane & 15;
    const int* rp; const int* csr; float* agg; int coloff;
    if (wid < N_NODES) { rp = rp_in; csr = csr_in; agg = agg_in; coloff = 0; }
    else { wid -= N_NODES; rp = rp_out; csr = csr_out; agg = agg_out; coloff = HALF; }
    const int node = rfl(wid);
    const int r0 = rfl(rp[node]);
    const int r1 = rfl(rp[node + 1]);
    const float* Pb = P + coloff + c4 * 4;
    float4 acc = make_float4(0.0f, 0.0f, 0.0f, 0.0f);
    for (int j = r0; j < r1; j += 4) {
        int jc = j + sub;
        int idx = csr[jc < r1 ? jc : r1 - 1];
        float m = (jc < r1) ? 1.0f : 0.0f;
        const float4 v = *reinterpret_cast<const float4*>(Pb + (size_t)idx * D);
        acc.x = fmaf(m, v.x, acc.x);
        acc.y = fmaf(m, v.y, acc.y);
        acc.z = fmaf(m, v.z, acc.z);
        acc.w = fmaf(m, v.w, acc.w);
    }
    acc.x += __shfl_xor(acc.x, 16, 64); acc.x += __shfl_xor(acc.x, 32, 64);
    acc.y += __shfl_xor(acc.y, 16, 64); acc.y += __shfl_xor(acc.y, 32, 64);
    acc.z += __shfl_xor(acc.z, 16, 64); acc.z += __shfl_xor(acc.z, 32, 64);
    acc.w += __shfl_xor(acc.w, 16, 64); acc.w += __shfl_xor(acc.w, 32, 64);
    float inv = 1.0f / fmaxf((float)(r1 - r0), 1.0f);
    if (sub == 0) {
        *reinterpret_cast<float4*>(agg + (size_t)node * HALF + c4 * 4) =
            make_float4(acc.x * inv, acc.y * inv, acc.z * inv, acc.w * inv);
    }
}

// Fused SAGE layer (post-aggregation):
//   h_in  = relu(agg_in  + x@Wr_in  + bl_in)    (agg already = mean@Wl)
//   h_out = relu(agg_out + x@Wr_out + bl_out)
//   x_new = relu([x | h_in | h_out] @ cW + cb)   (or final head if final_W)
// x rows staged wave-private in LDS; merged k-loop does Wr_in/Wr_out/cW-x;
// h overwrites the same LDS rows for the cW-h loop.
__global__ __launch_bounds__(256) void fused_layer_kernel(
    const float* __restrict__ X,
    const float* __restrict__ agg_in, const float* __restrict__ agg_out,
    const float* __restrict__ Wr_in, const float* __restrict__ bl_in,
    const float* __restrict__ Wr_out, const float* __restrict__ bl_out,
    const float* __restrict__ cW, const float* __restrict__ cb,
    float* __restrict__ xout,
    const float* __restrict__ final_W, const float* __restrict__ final_b,
    float* __restrict__ final_out)
{
    __shared__ alignas(16) float ls[NPB][D];   // 16 KB
    const int tid = threadIdx.x;
    const int wave = tid >> 6;
    const int lane = tid & 63;
    const int node0 = rfl(blockIdx.x * NPB + wave * NPW);

    // stage x rows (wave-private)
#pragma unroll
    for (int r = 0; r < 4; ++r) {
        int f = lane + 64 * r;
        int rl = f >> 5;
        int c4 = f & 31;
        int nn = node0 + rl; if (nn > N_NODES - 1) nn = N_NODES - 1;
        *reinterpret_cast<float4*>(&ls[wave * NPW + rl][c4 * 4]) =
            *reinterpret_cast<const float4*>(X + (size_t)nn * D + c4 * 4);
    }

    float ci[NPW], co[NPW], a0[NPW], a1[NPW];
    {
        const float cb0 = cb[lane], cb1 = cb[HALF + lane];
#pragma unroll
        for (int i = 0; i < NPW; ++i) { ci[i] = 0.0f; co[i] = 0.0f; a0[i] = cb0; a1[i] = cb1; }
    }

    // merged loop: conv-Wr (ci,co) + combine-x (a0,a1), single x read
    for (int k0 = 0; k0 < D; k0 += 4) {
        float wri[4], wro[4], c0[4], c1[4];
#pragma unroll
        for (int j = 0; j < 4; ++j) {
            int wh = (k0 + j) * HALF + lane;
            int wf = (k0 + j) * D + lane;
            wri[j] = Wr_in[wh]; wro[j] = Wr_out[wh];
            c0[j] = cW[wf]; c1[j] = cW[wf + HALF];
        }
#pragma unroll
        for (int i = 0; i < NPW; ++i) {
            const float4 xi = *reinterpret_cast<const float4*>(&ls[wave * NPW + i][k0]);
            ci[i] = fmaf(xi.x, wri[0], fmaf(xi.y, wri[1], fmaf(xi.z, wri[2], fmaf(xi.w, wri[3], ci[i]))));
            co[i] = fmaf(xi.x, wro[0], fmaf(xi.y, wro[1], fmaf(xi.z, wro[2], fmaf(xi.w, wro[3], co[i]))));
            a0[i] = fmaf(xi.x, c0[0], fmaf(xi.y, c0[1], fmaf(xi.z, c0[2], fmaf(xi.w, c0[3], a0[i]))));
            a1[i] = fmaf(xi.x, c1[0], fmaf(xi.y, c1[1], fmaf(xi.z, c1[2], fmaf(xi.w, c1[3], a1[i]))));
        }
    }

    // h phase: add aggregate + bias, relu, store into same LDS rows
    {
        const float bi = bl_in[lane], bo = bl_out[lane];
#pragma unroll
        for (int i = 0; i < NPW; ++i) {
            int nn = node0 + i; if (nn > N_NODES - 1) nn = N_NODES - 1;
            float hin  = fmaxf(ci[i] + agg_in[(size_t)nn * HALF + lane] + bi, 0.0f);
            float hout = fmaxf(co[i] + agg_out[(size_t)nn * HALF + lane] + bo, 0.0f);
            ls[wave * NPW + i][lane]        = hin;
            ls[wave * NPW + i][HALF + lane] = hout;
        }
    }

    // combine-h loop: cW rows 128..255
    for (int k0 = 0; k0 < D; k0 += 4) {
        float h0[4], h1[4];
#pragma unroll
        for (int j = 0; j < 4; ++j) {
            int wf = (D + k0 + j) * D + lane;
            h0[j] = cW[wf]; h1[j] = cW[wf + HALF];
        }
#pragma unroll
        for (int i = 0; i < NPW; ++i) {
            const float4 hi = *reinterpret_cast<const float4*>(&ls[wave * NPW + i][k0]);
            a0[i] = fmaf(hi.x, h0[0], fmaf(hi.y, h0[1], fmaf(hi.z, h0[2], fmaf(hi.w, h0[3], a0[i]))));
            a1[i] = fmaf(hi.x, h1[0], fmaf(hi.y, h1[1], fmaf(hi.z, h1[2], fmaf(hi.w, h1[3], a1[i]))));
        }
    }

    if (final_W == nullptr) {
#pragma unroll
        for (int i = 0; i < NPW; ++i) {
            int nn = node0 + i;
            if (nn < N_NODES) {
                xout[(size_t)nn * D + lane]        = fmaxf(a0[i], 0.0f);
                xout[(size_t)nn * D + HALF + lane] = fmaxf(a1[i], 0.0f);
            }
        }
    } else {
        const float fw0 = final_W[lane], fw1 = final_W[HALF + lane];
        const float fb = final_b[0];
#pragma unroll
        for (int i = 0; i < NPW; ++i) {
            float v = fmaxf(a0[i], 0.0f) * fw0 + fmaxf(a1[i], 0.0f) * fw1;
#pragma unroll
            for (int off = 32; off > 0; off >>= 1) v += __shfl_xor(v, off, 64);
            if (lane == 0 && node0 + i < N_NODES) final_out[node0 + i] = v + fb;
        }
    }
}

extern "C" void kernel_launch(void* const* d_in, const int* in_sizes, int n_in,
                              void* d_out, int out_size, void* d_ws, size_t ws_size,
                              hipStream_t stream) {
    const float* x       = (const float*)d_in[0];
    const int*   ei_in   = (const int*)d_in[1];
    const int*   ei_out  = (const int*)d_in[2];
    const float* in_Wl0  = (const float*)d_in[3];
    const float* in_bl0  = (const float*)d_in[4];
    const float* in_Wr0  = (const float*)d_in[5];
    const float* out_Wl0 = (const float*)d_in[6];
    const float* out_bl0 = (const float*)d_in[7];
    const float* out_Wr0 = (const float*)d_in[8];
    const float* comb_W0 = (const float*)d_in[9];
    const float* comb_b0 = (const float*)d_in[10];
    const float* in_Wl1  = (const float*)d_in[11];
    const float* in_bl1  = (const float*)d_in[12];
    const float* in_Wr1  = (const float*)d_in[13];
    const float* out_Wl1 = (const float*)d_in[14];
    const float* out_bl1 = (const float*)d_in[15];
    const float* out_Wr1 = (const float*)d_in[16];
    const float* comb_W1 = (const float*)d_in[17];
    const float* comb_b1 = (const float*)d_in[18];
    const float* final_W = (const float*)d_in[19];
    const float* final_b = (const float*)d_in[20];
    float* out = (float*)d_out;

    const size_t nd = (size_t)N_NODES * D;
    float* ws    = (float*)d_ws;
    float* P     = ws;                 // [N,128] transformed (x@[Wl_in|Wl_out])
    float* AGI   = P + nd;             // agg_in  [N,64]
    float* AGO   = AGI + nd / 2;       // agg_out [N,64]
    float* X1    = AGO + nd / 2;       // layer-0 output [N,128]
    int* rp_in   = (int*)(X1 + nd);          // N+1
    int* rp_out  = rp_in + (N_NODES + 1);    // N+1
    int* cur_in  = rp_out + (N_NODES + 1);   // N
    int* cur_out = cur_in + N_NODES;         // N
    int* csr_in  = cur_out + N_NODES;        // E
    int* csr_out = csr_in + E_EDGES;         // E

    const dim3 blk(256);
    const int edge2_grid = (2 * E_EDGES + 255) / 256;       // 4883
    const int pull_grid  = (2 * N_NODES * 64) / 256;        // 25000, exact
    const int node_grid  = (N_NODES + NPB - 1) / NPB;       // 1563

    // ---- CSR build (once, shared by both layers) ----
    zero_int_kernel<<<64, blk, 0, stream>>>(cur_in, 2 * N_NODES);
    hist2_kernel<<<edge2_grid, blk, 0, stream>>>(ei_in, ei_out, cur_in, cur_out);
    scan2_kernel<<<2, 1024, 0, stream>>>(cur_in, cur_out, rp_in, rp_out, N_NODES);
    csr_build2_kernel<<<edge2_grid, blk, 0, stream>>>(ei_in, ei_out, cur_in, cur_out, csr_in, csr_out);

    // ---- layer 0 ----
    transform_kernel<<<node_grid, blk, 0, stream>>>(x, in_Wl0, out_Wl0, P);
    pull_dual_kernel<<<pull_grid, blk, 0, stream>>>(P, rp_in, csr_in, rp_out, csr_out, AGI, AGO);
    fused_layer_kernel<<<node_grid, blk, 0, stream>>>(
        x, AGI, AGO, in_Wr0, in_bl0, out_Wr0, out_bl0,
        comb_W0, comb_b0, X1, nullptr, nullptr, nullptr);

    // ---- layer 1 (+ fused final head) ----
    transform_kernel<<<node_grid, blk, 0, stream>>>(X1, in_Wl1, out_Wl1, P);
    pull_dual_kernel<<<pull_grid, blk, 0, stream>>>(P, rp_in, csr_in, rp_out, csr_out, AGI, AGO);
    fused_layer_kernel<<<node_grid, blk, 0, stream>>>(
        X1, AGI, AGO, in_Wr1, in_bl1, out_Wr1, out_bl1,
        comb_W1, comb_b1, nullptr, final_W, final_b, out);
}

// Round 6
// 502.225 us; speedup vs baseline: 11.0194x; 1.0534x over previous
//
#include <hip/hip_runtime.h>
#include <hip/hip_fp16.h>

#define N_NODES 50000
#define D 128
#define HALF 64
#define E_EDGES 625000
#define NPB 32   // nodes per block (4 waves x 8 nodes)
#define NPW 8    // nodes per wave
#define EDGE2_GRID ((2 * E_EDGES + 255) / 256)   // 4883
#define NODE_GRID ((N_NODES + NPB - 1) / NPB)    // 1563

__device__ __forceinline__ int rfl(int v) { return __builtin_amdgcn_readfirstlane(v); }

__global__ void zero_int_kernel(int* __restrict__ p, int n) {
    int i = blockIdx.x * blockDim.x + threadIdx.x;
    int stride = gridDim.x * blockDim.x;
    for (; i < n; i += stride) p[i] = 0;
}

// Heterogeneous launch: blocks [0, EDGE2_GRID) histogram destinations of both
// edge sets (atomic/L2-bound); blocks [EDGE2_GRID, +NODE_GRID) compute
// P = X @ [Wl_a | Wl_b] in fp16 (VALU-bound). The two block types co-schedule.
__global__ __launch_bounds__(256) void hist_transform_kernel(
    const int* __restrict__ ei_in, const int* __restrict__ ei_out,
    int* __restrict__ deg_in, int* __restrict__ deg_out,
    const float* __restrict__ X,
    const float* __restrict__ Wl_a, const float* __restrict__ Wl_b,
    __half* __restrict__ P)
{
    if ((int)blockIdx.x < EDGE2_GRID) {
        int e = blockIdx.x * blockDim.x + threadIdx.x;
        if (e < E_EDGES) {
            atomicAdd(&deg_in[ei_in[E_EDGES + e]], 1);
        } else if (e < 2 * E_EDGES) {
            atomicAdd(&deg_out[ei_out[e]], 1);   // = ei_out[E_EDGES + (e-E_EDGES)]
        }
        return;
    }
    // ---- transform part ----
    __shared__ alignas(16) float ls[NPB][D];   // 16 KB
    const int bid = blockIdx.x - EDGE2_GRID;
    const int tid = threadIdx.x;
    const int wave = tid >> 6;
    const int lane = tid & 63;
    const int node0 = rfl(bid * NPB + wave * NPW);

#pragma unroll
    for (int r = 0; r < 4; ++r) {              // stage 8 rows, wave-private
        int f = lane + 64 * r;
        int rl = f >> 5;
        int c4 = f & 31;
        int nn = node0 + rl; if (nn > N_NODES - 1) nn = N_NODES - 1;
        *reinterpret_cast<float4*>(&ls[wave * NPW + rl][c4 * 4]) =
            *reinterpret_cast<const float4*>(X + (size_t)nn * D + c4 * 4);
    }

    float ta[NPW], tb[NPW];
#pragma unroll
    for (int i = 0; i < NPW; ++i) { ta[i] = 0.0f; tb[i] = 0.0f; }

    for (int k0 = 0; k0 < D; k0 += 4) {
        float wa[4], wb[4];
#pragma unroll
        for (int j = 0; j < 4; ++j) {
            int w = (k0 + j) * HALF + lane;
            wa[j] = Wl_a[w]; wb[j] = Wl_b[w];
        }
#pragma unroll
        for (int i = 0; i < NPW; ++i) {
            const float4 xi = *reinterpret_cast<const float4*>(&ls[wave * NPW + i][k0]);
            ta[i] = fmaf(xi.x, wa[0], fmaf(xi.y, wa[1], fmaf(xi.z, wa[2], fmaf(xi.w, wa[3], ta[i]))));
            tb[i] = fmaf(xi.x, wb[0], fmaf(xi.y, wb[1], fmaf(xi.z, wb[2], fmaf(xi.w, wb[3], tb[i]))));
        }
    }
#pragma unroll
    for (int i = 0; i < NPW; ++i) {
        int nn = node0 + i;
        if (nn < N_NODES) {
            P[(size_t)nn * D + lane]        = __float2half(ta[i]);
            P[(size_t)nn * D + HALF + lane] = __float2half(tb[i]);
        }
    }
}

// Shuffle-based exclusive scan: deg -> rowptr (rowptr[n]=total), cursor = excl prefix.
__global__ void scan2_kernel(int* __restrict__ cur_in, int* __restrict__ cur_out,
                             int* __restrict__ rp_in, int* __restrict__ rp_out, int n) {
    int* cur = blockIdx.x ? cur_out : cur_in;
    int* rp  = blockIdx.x ? rp_out  : rp_in;
    __shared__ int wsum[16];
    __shared__ int carry_s;
    const int tid = threadIdx.x;
    const int wave = tid >> 6;
    const int lane = tid & 63;
    if (tid == 0) carry_s = 0;
    __syncthreads();
    for (int base = 0; base < n; base += 1024) {
        int i = base + tid;
        int v = (i < n) ? cur[i] : 0;
        int s = v;
#pragma unroll
        for (int off = 1; off <= 32; off <<= 1) {
            int t = __shfl_up(s, off, 64);
            if (lane >= off) s += t;
        }
        if (lane == 63) wsum[wave] = s;
        __syncthreads();
        if (wave == 0 && lane < 16) {
            int ws = wsum[lane];
#pragma unroll
            for (int off = 1; off <= 8; off <<= 1) {
                int t = __shfl_up(ws, off, 64);
                if (lane >= off) ws += t;
            }
            wsum[lane] = ws;
        }
        __syncthreads();
        int waveoff = (wave == 0) ? 0 : wsum[wave - 1];
        int carry = carry_s;
        if (i < n) {
            int excl = carry + waveoff + s - v;
            rp[i] = excl;
            cur[i] = excl;
        }
        __syncthreads();
        if (tid == 0) carry_s = carry + wsum[15];
        __syncthreads();
    }
    if (tid == 0) rp[n] = carry_s;
}

// Scatter both edge sets into CSR adjacency (by destination) in one launch.
__global__ void csr_build2_kernel(const int* __restrict__ ei_in, const int* __restrict__ ei_out,
                                  int* __restrict__ cur_in, int* __restrict__ cur_out,
                                  int* __restrict__ csr_in, int* __restrict__ csr_out) {
    int e = blockIdx.x * blockDim.x + threadIdx.x;
    if (e < E_EDGES) {
        int src = ei_in[e], dst = ei_in[E_EDGES + e];
        csr_in[atomicAdd(&cur_in[dst], 1)] = src;
    } else if (e < 2 * E_EDGES) {
        int src = ei_out[e - E_EDGES], dst = ei_out[e];
        csr_out[atomicAdd(&cur_out[dst], 1)] = src;
    }
}

// Mean-aggregate fp16 64-wide halves of P. One wave per (node, dir).
// 8 edges in flight: sub = lane>>3 picks the edge, c = lane&7 picks a
// 16B half8 chunk (8 lanes x 16B = one 128B row). fp32 accumulate,
// 3-step shfl_xor reduce over subs, fp32 mean written by sub 0.
__global__ __launch_bounds__(256) void pull_dual_kernel(
    const __half* __restrict__ P,
    const int* __restrict__ rp_in, const int* __restrict__ csr_in,
    const int* __restrict__ rp_out, const int* __restrict__ csr_out,
    float* __restrict__ agg_in, float* __restrict__ agg_out)
{
    int gid = blockIdx.x * blockDim.x + threadIdx.x;
    int wid = gid >> 6;
    const int lane = gid & 63;
    const int sub = lane >> 3;
    const int c = lane & 7;
    const int* rp; const int* csr; float* agg; int coloff;
    if (wid < N_NODES) { rp = rp_in; csr = csr_in; agg = agg_in; coloff = 0; }
    else { wid -= N_NODES; rp = rp_out; csr = csr_out; agg = agg_out; coloff = HALF; }
    const int node = rfl(wid);
    const int r0 = rfl(rp[node]);
    const int r1 = rfl(rp[node + 1]);
    const __half* Pb = P + coloff + c * 8;
    float acc[8];
#pragma unroll
    for (int t = 0; t < 8; ++t) acc[t] = 0.0f;
    for (int j = r0; j < r1; j += 8) {
        int jc = j + sub;
        int idx = csr[jc < r1 ? jc : r1 - 1];
        float m = (jc < r1) ? 1.0f : 0.0f;
        uint4 raw = *reinterpret_cast<const uint4*>(Pb + (size_t)idx * D);
        const __half2 h0 = *reinterpret_cast<const __half2*>(&raw.x);
        const __half2 h1 = *reinterpret_cast<const __half2*>(&raw.y);
        const __half2 h2 = *reinterpret_cast<const __half2*>(&raw.z);
        const __half2 h3 = *reinterpret_cast<const __half2*>(&raw.w);
        float2 f0 = __half22float2(h0), f1 = __half22float2(h1);
        float2 f2 = __half22float2(h2), f3 = __half22float2(h3);
        acc[0] = fmaf(m, f0.x, acc[0]); acc[1] = fmaf(m, f0.y, acc[1]);
        acc[2] = fmaf(m, f1.x, acc[2]); acc[3] = fmaf(m, f1.y, acc[3]);
        acc[4] = fmaf(m, f2.x, acc[4]); acc[5] = fmaf(m, f2.y, acc[5]);
        acc[6] = fmaf(m, f3.x, acc[6]); acc[7] = fmaf(m, f3.y, acc[7]);
    }
#pragma unroll
    for (int t = 0; t < 8; ++t) {
        acc[t] += __shfl_xor(acc[t], 8, 64);
        acc[t] += __shfl_xor(acc[t], 16, 64);
        acc[t] += __shfl_xor(acc[t], 32, 64);
    }
    if (sub == 0) {
        float inv = 1.0f / fmaxf((float)(r1 - r0), 1.0f);
        float* ab = agg + (size_t)node * HALF + c * 8;
        *reinterpret_cast<float4*>(ab)     = make_float4(acc[0]*inv, acc[1]*inv, acc[2]*inv, acc[3]*inv);
        *reinterpret_cast<float4*>(ab + 4) = make_float4(acc[4]*inv, acc[5]*inv, acc[6]*inv, acc[7]*inv);
    }
}

// Fused SAGE layer (post-aggregation):
//   h_in  = relu(agg_in  + x@Wr_in  + bl_in), h_out likewise
//   x_new = relu([x | h_in | h_out] @ cW + cb)
// Then either (a) write x_new + compute next layer's P = x_new@[nWl_a|nWl_b]
// with x_new staged through LDS (layer 0), or (b) final head (layer 1).
__global__ __launch_bounds__(256) void fused_layer_kernel(
    const float* __restrict__ X,
    const float* __restrict__ agg_in, const float* __restrict__ agg_out,
    const float* __restrict__ Wr_in, const float* __restrict__ bl_in,
    const float* __restrict__ Wr_out, const float* __restrict__ bl_out,
    const float* __restrict__ cW, const float* __restrict__ cb,
    float* __restrict__ xout,
    const float* __restrict__ nWl_a, const float* __restrict__ nWl_b,
    __half* __restrict__ nP,
    const float* __restrict__ final_W, const float* __restrict__ final_b,
    float* __restrict__ final_out)
{
    __shared__ alignas(16) float ls[NPB][D];   // 16 KB
    const int tid = threadIdx.x;
    const int wave = tid >> 6;
    const int lane = tid & 63;
    const int node0 = rfl(blockIdx.x * NPB + wave * NPW);

#pragma unroll
    for (int r = 0; r < 4; ++r) {              // stage x rows (wave-private)
        int f = lane + 64 * r;
        int rl = f >> 5;
        int c4 = f & 31;
        int nn = node0 + rl; if (nn > N_NODES - 1) nn = N_NODES - 1;
        *reinterpret_cast<float4*>(&ls[wave * NPW + rl][c4 * 4]) =
            *reinterpret_cast<const float4*>(X + (size_t)nn * D + c4 * 4);
    }

    float ci[NPW], co[NPW], a0[NPW], a1[NPW];
    {
        const float cb0 = cb[lane], cb1 = cb[HALF + lane];
#pragma unroll
        for (int i = 0; i < NPW; ++i) { ci[i] = 0.0f; co[i] = 0.0f; a0[i] = cb0; a1[i] = cb1; }
    }

    // merged loop: conv-Wr (ci,co) + combine-x (a0,a1), single x read
    for (int k0 = 0; k0 < D; k0 += 4) {
        float wri[4], wro[4], c0[4], c1[4];
#pragma unroll
        for (int j = 0; j < 4; ++j) {
            int wh = (k0 + j) * HALF + lane;
            int wf = (k0 + j) * D + lane;
            wri[j] = Wr_in[wh]; wro[j] = Wr_out[wh];
            c0[j] = cW[wf]; c1[j] = cW[wf + HALF];
        }
#pragma unroll
        for (int i = 0; i < NPW; ++i) {
            const float4 xi = *reinterpret_cast<const float4*>(&ls[wave * NPW + i][k0]);
            ci[i] = fmaf(xi.x, wri[0], fmaf(xi.y, wri[1], fmaf(xi.z, wri[2], fmaf(xi.w, wri[3], ci[i]))));
            co[i] = fmaf(xi.x, wro[0], fmaf(xi.y, wro[1], fmaf(xi.z, wro[2], fmaf(xi.w, wro[3], co[i]))));
            a0[i] = fmaf(xi.x, c0[0], fmaf(xi.y, c0[1], fmaf(xi.z, c0[2], fmaf(xi.w, c0[3], a0[i]))));
            a1[i] = fmaf(xi.x, c1[0], fmaf(xi.y, c1[1], fmaf(xi.z, c1[2], fmaf(xi.w, c1[3], a1[i]))));
        }
    }

    // h phase: add aggregate + bias, relu, store into same LDS rows
    {
        const float bi = bl_in[lane], bo = bl_out[lane];
#pragma unroll
        for (int i = 0; i < NPW; ++i) {
            int nn = node0 + i; if (nn > N_NODES - 1) nn = N_NODES - 1;
            float hin  = fmaxf(ci[i] + agg_in[(size_t)nn * HALF + lane] + bi, 0.0f);
            float hout = fmaxf(co[i] + agg_out[(size_t)nn * HALF + lane] + bo, 0.0f);
            ls[wave * NPW + i][lane]        = hin;
            ls[wave * NPW + i][HALF + lane] = hout;
        }
    }

    // combine-h loop: cW rows 128..255
    for (int k0 = 0; k0 < D; k0 += 4) {
        float h0[4], h1[4];
#pragma unroll
        for (int j = 0; j < 4; ++j) {
            int wf = (D + k0 + j) * D + lane;
            h0[j] = cW[wf]; h1[j] = cW[wf + HALF];
        }
#pragma unroll
        for (int i = 0; i < NPW; ++i) {
            const float4 hi = *reinterpret_cast<const float4*>(&ls[wave * NPW + i][k0]);
            a0[i] = fmaf(hi.x, h0[0], fmaf(hi.y, h0[1], fmaf(hi.z, h0[2], fmaf(hi.w, h0[3], a0[i]))));
            a1[i] = fmaf(hi.x, h1[0], fmaf(hi.y, h1[1], fmaf(hi.z, h1[2], fmaf(hi.w, h1[3], a1[i]))));
        }
    }

    if (final_W == nullptr) {
        // write x_new and restage it into LDS for the fused next-layer transform
#pragma unroll
        for (int i = 0; i < NPW; ++i) {
            int nn = node0 + i;
            float r0v = fmaxf(a0[i], 0.0f);
            float r1v = fmaxf(a1[i], 0.0f);
            if (nn < N_NODES) {
                xout[(size_t)nn * D + lane]        = r0v;
                xout[(size_t)nn * D + HALF + lane] = r1v;
            }
            ls[wave * NPW + i][lane]        = r0v;
            ls[wave * NPW + i][HALF + lane] = r1v;
        }
        // transform: nP = x_new @ [nWl_a | nWl_b], fp16 output
        float ta[NPW], tb[NPW];
#pragma unroll
        for (int i = 0; i < NPW; ++i) { ta[i] = 0.0f; tb[i] = 0.0f; }
        for (int k0 = 0; k0 < D; k0 += 4) {
            float wa[4], wb[4];
#pragma unroll
            for (int j = 0; j < 4; ++j) {
                int w = (k0 + j) * HALF + lane;
                wa[j] = nWl_a[w]; wb[j] = nWl_b[w];
            }
#pragma unroll
            for (int i = 0; i < NPW; ++i) {
                const float4 xi = *reinterpret_cast<const float4*>(&ls[wave * NPW + i][k0]);
                ta[i] = fmaf(xi.x, wa[0], fmaf(xi.y, wa[1], fmaf(xi.z, wa[2], fmaf(xi.w, wa[3], ta[i]))));
                tb[i] = fmaf(xi.x, wb[0], fmaf(xi.y, wb[1], fmaf(xi.z, wb[2], fmaf(xi.w, wb[3], tb[i]))));
            }
        }
#pragma unroll
        for (int i = 0; i < NPW; ++i) {
            int nn = node0 + i;
            if (nn < N_NODES) {
                nP[(size_t)nn * D + lane]        = __float2half(ta[i]);
                nP[(size_t)nn * D + HALF + lane] = __float2half(tb[i]);
            }
        }
    } else {
        const float fw0 = final_W[lane], fw1 = final_W[HALF + lane];
        const float fb = final_b[0];
#pragma unroll
        for (int i = 0; i < NPW; ++i) {
            float v = fmaxf(a0[i], 0.0f) * fw0 + fmaxf(a1[i], 0.0f) * fw1;
#pragma unroll
            for (int off = 32; off > 0; off >>= 1) v += __shfl_xor(v, off, 64);
            if (lane == 0 && node0 + i < N_NODES) final_out[node0 + i] = v + fb;
        }
    }
}

extern "C" void kernel_launch(void* const* d_in, const int* in_sizes, int n_in,
                              void* d_out, int out_size, void* d_ws, size_t ws_size,
                              hipStream_t stream) {
    const float* x       = (const float*)d_in[0];
    const int*   ei_in   = (const int*)d_in[1];
    const int*   ei_out  = (const int*)d_in[2];
    const float* in_Wl0  = (const float*)d_in[3];
    const float* in_bl0  = (const float*)d_in[4];
    const float* in_Wr0  = (const float*)d_in[5];
    const float* out_Wl0 = (const float*)d_in[6];
    const float* out_bl0 = (const float*)d_in[7];
    const float* out_Wr0 = (const float*)d_in[8];
    const float* comb_W0 = (const float*)d_in[9];
    const float* comb_b0 = (const float*)d_in[10];
    const float* in_Wl1  = (const float*)d_in[11];
    const float* in_bl1  = (const float*)d_in[12];
    const float* in_Wr1  = (const float*)d_in[13];
    const float* out_Wl1 = (const float*)d_in[14];
    const float* out_bl1 = (const float*)d_in[15];
    const float* out_Wr1 = (const float*)d_in[16];
    const float* comb_W1 = (const float*)d_in[17];
    const float* comb_b1 = (const float*)d_in[18];
    const float* final_W = (const float*)d_in[19];
    const float* final_b = (const float*)d_in[20];
    float* out = (float*)d_out;

    const size_t nd = (size_t)N_NODES * D;
    float* ws    = (float*)d_ws;
    float* AGI   = ws;                 // agg_in  [N,64] f32
    float* AGO   = AGI + nd / 2;       // agg_out [N,64] f32
    float* X1    = AGO + nd / 2;       // layer-0 output [N,128] f32
    int* rp_in   = (int*)(X1 + nd);          // N+1
    int* rp_out  = rp_in + (N_NODES + 1);    // N+1
    int* cur_in  = rp_out + (N_NODES + 1);   // N
    int* cur_out = cur_in + N_NODES;         // N
    int* csr_in  = cur_out + N_NODES;        // E
    int* csr_out = csr_in + E_EDGES;         // E
    __half* P    = (__half*)(csr_out + E_EDGES);   // [N,128] fp16

    const dim3 blk(256);
    const int pull_grid = (2 * N_NODES * 64) / 256;        // 25000, exact

    // ---- CSR build + layer-0 transform overlapped ----
    zero_int_kernel<<<64, blk, 0, stream>>>(cur_in, 2 * N_NODES);
    hist_transform_kernel<<<EDGE2_GRID + NODE_GRID, blk, 0, stream>>>(
        ei_in, ei_out, cur_in, cur_out, x, in_Wl0, out_Wl0, P);
    scan2_kernel<<<2, 1024, 0, stream>>>(cur_in, cur_out, rp_in, rp_out, N_NODES);
    csr_build2_kernel<<<EDGE2_GRID, blk, 0, stream>>>(ei_in, ei_out, cur_in, cur_out, csr_in, csr_out);

    // ---- layer 0 (fused layer also computes layer-1 P) ----
    pull_dual_kernel<<<pull_grid, blk, 0, stream>>>(P, rp_in, csr_in, rp_out, csr_out, AGI, AGO);
    fused_layer_kernel<<<NODE_GRID, blk, 0, stream>>>(
        x, AGI, AGO, in_Wr0, in_bl0, out_Wr0, out_bl0,
        comb_W0, comb_b0, X1, in_Wl1, out_Wl1, P, nullptr, nullptr, nullptr);

    // ---- layer 1 (+ fused final head) ----
    pull_dual_kernel<<<pull_grid, blk, 0, stream>>>(P, rp_in, csr_in, rp_out, csr_out, AGI, AGO);
    fused_layer_kernel<<<NODE_GRID, blk, 0, stream>>>(
        X1, AGI, AGO, in_Wr1, in_bl1, out_Wr1, out_bl1,
        comb_W1, comb_b1, nullptr, nullptr, nullptr, nullptr, final_W, final_b, out);
}

// Round 7
// 335.410 us; speedup vs baseline: 16.4999x; 1.4973x over previous
//
#include <hip/hip_runtime.h>
#include <hip/hip_fp16.h>

#define N_NODES 50000
#define D 128
#define HALF 64
#define E_EDGES 625000
#define EDGE2_GRID ((2 * E_EDGES + 255) / 256)       // 4883
#define M_BLK 64
#define NODE64_GRID ((N_NODES + M_BLK - 1) / M_BLK)  // 782

typedef unsigned short ushortT;
using f16     = _Float16;
using half8   = __attribute__((ext_vector_type(8))) _Float16;
using half4v  = __attribute__((ext_vector_type(4))) _Float16;
using floatx4 = __attribute__((ext_vector_type(4))) float;

__device__ __forceinline__ int rfl(int v) { return __builtin_amdgcn_readfirstlane(v); }
__device__ __forceinline__ floatx4 mfma16(half8 a, half8 b, floatx4 c) {
    return __builtin_amdgcn_mfma_f32_16x16x32_f16(a, b, c, 0, 0, 0);
}

// A-fragment read from swizzled wave-private LDS tile [16 rows][128 f16].
// Swizzle: 16B chunk cc stored at chunk (cc ^ (row&7)). A: row = lane&15,
// k = (lane>>4)*8 + j  ->  chunk cc = ks*4 + (lane>>4).
__device__ __forceinline__ half8 ldsA(const f16 (*Xw)[D], int lane, int ks) {
    int r = lane & 15;
    int cc = ks * 4 + (lane >> 4);
    return *(const half8*)&Xw[r][((cc ^ (r & 7)) << 3)];
}

// Stage 16 fp32 rows -> fp16 swizzled LDS (wave-private).
__device__ __forceinline__ void stage_f32(f16 (*Xw)[D], const float* __restrict__ X,
                                          int nodeBase, int lane) {
#pragma unroll
    for (int r4 = 0; r4 < 8; ++r4) {
        int s = lane + 64 * r4;            // 512 float4 slots = 16 rows x 32
        int row = s >> 5, c4 = s & 31;
        int nn = nodeBase + row; if (nn > N_NODES - 1) nn = N_NODES - 1;
        float4 v = *(const float4*)(X + (size_t)nn * D + c4 * 4);
        int cc = c4 >> 1;
        half4v pk = { (f16)v.x, (f16)v.y, (f16)v.z, (f16)v.w };
        *(half4v*)&Xw[row][((cc ^ (row & 7)) << 3) + ((c4 & 1) << 2)] = pk;
    }
}

// Stage 16 fp16 rows -> swizzled LDS (16B chunks).
__device__ __forceinline__ void stage_f16(f16 (*Xw)[D], const f16* __restrict__ X,
                                          int nodeBase, int lane) {
#pragma unroll
    for (int r = 0; r < 4; ++r) {
        int s = lane + 64 * r;             // 256 chunk slots = 16 rows x 16
        int row = s >> 4, cc = s & 15;
        int nn = nodeBase + row; if (nn > N_NODES - 1) nn = N_NODES - 1;
        uint4 v = *(const uint4*)(X + (size_t)nn * D + cc * 8);
        *(uint4*)&Xw[row][((cc ^ (row & 7)) << 3)] = v;
    }
}

// GEMM [16 x 128] = LDS-X @ packed-W(K=128), write fp16 result to Pout.
__device__ __forceinline__ void gemm_store_P(const f16 (*Xw)[D], const f16* __restrict__ Wp,
                                             f16* __restrict__ Pout, int nodeBase, int lane) {
    half8 a[4];
#pragma unroll
    for (int ks = 0; ks < 4; ++ks) a[ks] = ldsA(Xw, lane, ks);
#pragma unroll
    for (int ct = 0; ct < 8; ++ct) {
        floatx4 acc = {0.f, 0.f, 0.f, 0.f};
#pragma unroll
        for (int ks = 0; ks < 4; ++ks) {
            half8 b = *(const half8*)(Wp + (((ct * 4 + ks) * 64 + lane) << 3));
            acc = mfma16(a[ks], b, acc);
        }
        int col = ct * 16 + (lane & 15);
#pragma unroll
        for (int i = 0; i < 4; ++i) {
            int nn = nodeBase + (lane >> 4) * 4 + i;
            if (nn < N_NODES) Pout[(size_t)nn * D + col] = (f16)acc[i];
        }
    }
}

// prep: blocks 0..63 zero the 2N degree/cursor ints; blocks 64..127 pack all
// six weight matrices into MFMA B-fragment order:
//   pack[((ct*KS+ks)*64+lane)*8 + j] = W[k][c],  k = ks*32+(lane>>4)*8+j,
//   c = ct*16+(lane&15); dual weights: c<64 -> Wa[k][c], else Wb[k][c-64].
__global__ __launch_bounds__(256) void prep_kernel(
    int* __restrict__ cur,
    const float* iWr0, const float* oWr0, const float* iWl1, const float* oWl1,
    const float* iWr1, const float* oWr1, const float* iWl0, const float* oWl0,
    const float* cW0, const float* cW1,
    f16* Wr0p, f16* Wl1p, f16* Wr1p, f16* Wl0p, f16* cW0p, f16* cW1p)
{
    int b = blockIdx.x;
    if (b < 64) {
        for (int i = b * 256 + threadIdx.x; i < 2 * N_NODES; i += 64 * 256) cur[i] = 0;
        return;
    }
    b -= 64;
    if (b < 32) {   // dual K=128 packs: 4 weights x 8 blocks
        int w = b >> 3;
        int e = (b & 7) * 256 + threadIdx.x;          // [0, 2048)
        const float* Wa; const float* Wb; f16* dst;
        if (w == 0)      { Wa = iWr0; Wb = oWr0; dst = Wr0p; }
        else if (w == 1) { Wa = iWl1; Wb = oWl1; dst = Wl1p; }
        else if (w == 2) { Wa = iWr1; Wb = oWr1; dst = Wr1p; }
        else             { Wa = iWl0; Wb = oWl0; dst = Wl0p; }
        int lane = e & 63, ks = (e >> 6) & 3, ct = e >> 8;
        int k0 = ks * 32 + ((lane >> 4) << 3), c = ct * 16 + (lane & 15);
        half8 v;
#pragma unroll
        for (int j = 0; j < 8; ++j) {
            int k = k0 + j;
            float f = (c < 64) ? Wa[k * HALF + c] : Wb[k * HALF + (c - 64)];
            v[j] = (f16)f;
        }
        *(half8*)(dst + ((size_t)e << 3)) = v;
        return;
    }
    b -= 32;        // cW K=256 packs: 2 weights x 16 blocks
    {
        int w = b >> 4;
        int e = (b & 15) * 256 + threadIdx.x;         // [0, 4096)
        const float* W = w ? cW1 : cW0;
        f16* dst = w ? cW1p : cW0p;
        int lane = e & 63, ks = (e >> 6) & 7, ct = e >> 9;
        int k0 = ks * 32 + ((lane >> 4) << 3), c = ct * 16 + (lane & 15);
        half8 v;
#pragma unroll
        for (int j = 0; j < 8; ++j) v[j] = (f16)W[(size_t)(k0 + j) * D + c];
        *(half8*)(dst + ((size_t)e << 3)) = v;
    }
}

// Heterogeneous: hist blocks (atomic-bound) + MFMA transform of layer-0 P.
__global__ __launch_bounds__(256) void hist_transform_kernel(
    const int* __restrict__ ei_in, const int* __restrict__ ei_out,
    int* __restrict__ deg_in, int* __restrict__ deg_out,
    const float* __restrict__ X, const f16* __restrict__ Wl0p, f16* __restrict__ P)
{
    __shared__ f16 Xh[4][16][D];
    if ((int)blockIdx.x < EDGE2_GRID) {
        int e = blockIdx.x * 256 + threadIdx.x;
        if (e < E_EDGES) atomicAdd(&deg_in[ei_in[E_EDGES + e]], 1);
        else if (e < 2 * E_EDGES) atomicAdd(&deg_out[ei_out[e]], 1);
        return;
    }
    const int bid = blockIdx.x - EDGE2_GRID;
    const int tid = threadIdx.x, wave = tid >> 6, lane = tid & 63;
    const int nodeBase = bid * M_BLK + wave * 16;
    f16 (*Xw)[D] = Xh[wave];
    stage_f32(Xw, X, nodeBase, lane);
    gemm_store_P(Xw, Wl0p, P, nodeBase, lane);
}

// Shuffle-based exclusive scan: deg -> rowptr (rowptr[n]=total), cursor = excl prefix.
__global__ void scan2_kernel(int* __restrict__ cur_in, int* __restrict__ cur_out,
                             int* __restrict__ rp_in, int* __restrict__ rp_out, int n) {
    int* cur = blockIdx.x ? cur_out : cur_in;
    int* rp  = blockIdx.x ? rp_out  : rp_in;
    __shared__ int wsum[16];
    __shared__ int carry_s;
    const int tid = threadIdx.x;
    const int wave = tid >> 6;
    const int lane = tid & 63;
    if (tid == 0) carry_s = 0;
    __syncthreads();
    for (int base = 0; base < n; base += 1024) {
        int i = base + tid;
        int v = (i < n) ? cur[i] : 0;
        int s = v;
#pragma unroll
        for (int off = 1; off <= 32; off <<= 1) {
            int t = __shfl_up(s, off, 64);
            if (lane >= off) s += t;
        }
        if (lane == 63) wsum[wave] = s;
        __syncthreads();
        if (wave == 0 && lane < 16) {
            int ws = wsum[lane];
#pragma unroll
            for (int off = 1; off <= 8; off <<= 1) {
                int t = __shfl_up(ws, off, 64);
                if (lane >= off) ws += t;
            }
            wsum[lane] = ws;
        }
        __syncthreads();
        int waveoff = (wave == 0) ? 0 : wsum[wave - 1];
        int carry = carry_s;
        if (i < n) {
            int excl = carry + waveoff + s - v;
            rp[i] = excl;
            cur[i] = excl;
        }
        __syncthreads();
        if (tid == 0) carry_s = carry + wsum[15];
        __syncthreads();
    }
    if (tid == 0) rp[n] = carry_s;
}

// Scatter both edge sets into uint16 CSR adjacency (src < 50000 < 2^16).
__global__ void csr_build2_kernel(const int* __restrict__ ei_in, const int* __restrict__ ei_out,
                                  int* __restrict__ cur_in, int* __restrict__ cur_out,
                                  ushortT* __restrict__ csr_in, ushortT* __restrict__ csr_out) {
    int e = blockIdx.x * blockDim.x + threadIdx.x;
    if (e < E_EDGES) {
        int src = ei_in[e], dst = ei_in[E_EDGES + e];
        csr_in[atomicAdd(&cur_in[dst], 1)] = (ushortT)src;
    } else if (e < 2 * E_EDGES) {
        int src = ei_out[e - E_EDGES], dst = ei_out[e];
        csr_out[atomicAdd(&cur_out[dst], 1)] = (ushortT)src;
    }
}

// Mean-aggregate fp16 64-wide halves of P. One wave per (node, dir).
// 8 edges in flight: sub = lane>>3, c = lane&7 (16B half8 chunk per row).
__global__ __launch_bounds__(256) void pull_dual_kernel(
    const f16* __restrict__ P,
    const int* __restrict__ rp_in, const ushortT* __restrict__ csr_in,
    const int* __restrict__ rp_out, const ushortT* __restrict__ csr_out,
    float* __restrict__ agg_in, float* __restrict__ agg_out)
{
    int gid = blockIdx.x * blockDim.x + threadIdx.x;
    int wid = gid >> 6;
    const int lane = gid & 63;
    const int sub = lane >> 3;
    const int c = lane & 7;
    const int* rp; const ushortT* csr; float* agg; int coloff;
    if (wid < N_NODES) { rp = rp_in; csr = csr_in; agg = agg_in; coloff = 0; }
    else { wid -= N_NODES; rp = rp_out; csr = csr_out; agg = agg_out; coloff = HALF; }
    const int node = rfl(wid);
    const int r0 = rfl(rp[node]);
    const int r1 = rfl(rp[node + 1]);
    const f16* Pb = P + coloff + c * 8;
    float acc[8];
#pragma unroll
    for (int t = 0; t < 8; ++t) acc[t] = 0.0f;
    for (int j = r0; j < r1; j += 8) {
        int jc = j + sub;
        int idx = csr[jc < r1 ? jc : r1 - 1];
        float m = (jc < r1) ? 1.0f : 0.0f;
        half8 v = *(const half8*)(Pb + (size_t)idx * D);
#pragma unroll
        for (int t = 0; t < 8; ++t) acc[t] = fmaf(m, (float)v[t], acc[t]);
    }
#pragma unroll
    for (int t = 0; t < 8; ++t) {
        acc[t] += __shfl_xor(acc[t], 8, 64);
        acc[t] += __shfl_xor(acc[t], 16, 64);
        acc[t] += __shfl_xor(acc[t], 32, 64);
    }
    if (sub == 0) {
        float inv = 1.0f / fmaxf((float)(r1 - r0), 1.0f);
        float* ab = agg + (size_t)node * HALF + c * 8;
        *(float4*)ab       = make_float4(acc[0]*inv, acc[1]*inv, acc[2]*inv, acc[3]*inv);
        *(float4*)(ab + 4) = make_float4(acc[4]*inv, acc[5]*inv, acc[6]*inv, acc[7]*inv);
    }
}

// Fused MFMA SAGE layer: conv (X@[Wr_in|Wr_out] + agg + bias, relu) -> Hh LDS
// -> combine ([X|H]@cW + cb, relu) -> either {write X1 fp16 + next-layer P}
// or {final head}. All LDS is wave-private (no barriers).
__global__ __launch_bounds__(256) void fused_mfma_kernel(
    const float* __restrict__ Xf, const f16* __restrict__ X16,
    const float* __restrict__ AGI, const float* __restrict__ AGO,
    const f16* __restrict__ Wrp, const float* __restrict__ bl_in, const float* __restrict__ bl_out,
    const f16* __restrict__ cWp, const float* __restrict__ cb,
    f16* __restrict__ Xout16,
    const f16* __restrict__ Wlnp, f16* __restrict__ Pout,
    const float* __restrict__ fW, const float* __restrict__ fb, float* __restrict__ outv)
{
    __shared__ f16 Xh[4][16][D];
    __shared__ f16 Hh[4][16][D];
    const int tid = threadIdx.x, wave = tid >> 6, lane = tid & 63;
    const int nodeBase = blockIdx.x * M_BLK + wave * 16;
    f16 (*Xw)[D] = Xh[wave];
    f16 (*Hw)[D] = Hh[wave];
    const int colq = lane & 15;
    const int rq = lane >> 4;

    if (Xf) stage_f32(Xw, Xf, nodeBase, lane);
    else    stage_f16(Xw, X16, nodeBase, lane);

    half8 aX[4];
#pragma unroll
    for (int ks = 0; ks < 4; ++ks) aX[ks] = ldsA(Xw, lane, ks);

    // ---- conv: tiles ct<4 -> h_in cols, ct>=4 -> h_out cols ----
#pragma unroll
    for (int ct = 0; ct < 8; ++ct) {
        floatx4 acc = {0.f, 0.f, 0.f, 0.f};
#pragma unroll
        for (int ks = 0; ks < 4; ++ks) {
            half8 b = *(const half8*)(Wrp + (((ct * 4 + ks) * 64 + lane) << 3));
            acc = mfma16(aX[ks], b, acc);
        }
        int c64 = (ct & 3) * 16 + colq;
        const float* AG = (ct < 4) ? AGI : AGO;
        float bl = (ct < 4) ? bl_in[c64] : bl_out[c64];
        int colg = ct * 16 + colq;
        int cc = colg >> 3;
#pragma unroll
        for (int i = 0; i < 4; ++i) {
            int r16 = rq * 4 + i;
            int nn = nodeBase + r16; if (nn > N_NODES - 1) nn = N_NODES - 1;
            float h = acc[i] + AG[(size_t)nn * HALF + c64] + bl;
            Hw[r16][((cc ^ (r16 & 7)) << 3) + (colg & 7)] = (f16)fmaxf(h, 0.f);
        }
    }

    // ---- combine: [X | H] @ cW + cb ----
    floatx4 acc2[8];
#pragma unroll
    for (int ct = 0; ct < 8; ++ct) {
        float cbv = cb[ct * 16 + colq];
        floatx4 t = {cbv, cbv, cbv, cbv};
#pragma unroll
        for (int ks = 0; ks < 4; ++ks) {
            half8 b = *(const half8*)(cWp + (((ct * 8 + ks) * 64 + lane) << 3));
            t = mfma16(aX[ks], b, t);
        }
        acc2[ct] = t;
    }
    half8 aH[4];
#pragma unroll
    for (int ks = 0; ks < 4; ++ks) aH[ks] = ldsA(Hw, lane, ks);
#pragma unroll
    for (int ct = 0; ct < 8; ++ct) {
#pragma unroll
        for (int ks = 0; ks < 4; ++ks) {
            half8 b = *(const half8*)(cWp + (((ct * 8 + 4 + ks) * 64 + lane) << 3));
            acc2[ct] = mfma16(aH[ks], b, acc2[ct]);
        }
    }

    if (fW == nullptr) {
        // x_new: write fp16 global + restage into Xh for next-layer transform
#pragma unroll
        for (int ct = 0; ct < 8; ++ct) {
            int colg = ct * 16 + colq;
            int cc = colg >> 3;
#pragma unroll
            for (int i = 0; i < 4; ++i) {
                int r16 = rq * 4 + i;
                int nn = nodeBase + r16;
                f16 hv = (f16)fmaxf(acc2[ct][i], 0.f);
                if (nn < N_NODES) Xout16[(size_t)nn * D + colg] = hv;
                Xw[r16][((cc ^ (r16 & 7)) << 3) + (colg & 7)] = hv;
            }
        }
        gemm_store_P(Xw, Wlnp, Pout, nodeBase, lane);
    } else {
        // final head: out[node] = sum_c relu(X2[node][c]) * fW[c] + fb
        float fs0 = 0, fs1 = 0, fs2 = 0, fs3 = 0;
#pragma unroll
        for (int ct = 0; ct < 8; ++ct) {
            float fwv = fW[ct * 16 + colq];
            fs0 = fmaf(fmaxf(acc2[ct][0], 0.f), fwv, fs0);
            fs1 = fmaf(fmaxf(acc2[ct][1], 0.f), fwv, fs1);
            fs2 = fmaf(fmaxf(acc2[ct][2], 0.f), fwv, fs2);
            fs3 = fmaf(fmaxf(acc2[ct][3], 0.f), fwv, fs3);
        }
#pragma unroll
        for (int off = 1; off < 16; off <<= 1) {
            fs0 += __shfl_xor(fs0, off, 64);
            fs1 += __shfl_xor(fs1, off, 64);
            fs2 += __shfl_xor(fs2, off, 64);
            fs3 += __shfl_xor(fs3, off, 64);
        }
        if (colq == 0) {
            float fbv = fb[0];
            int nb = nodeBase + rq * 4;
            if (nb + 0 < N_NODES) outv[nb + 0] = fs0 + fbv;
            if (nb + 1 < N_NODES) outv[nb + 1] = fs1 + fbv;
            if (nb + 2 < N_NODES) outv[nb + 2] = fs2 + fbv;
            if (nb + 3 < N_NODES) outv[nb + 3] = fs3 + fbv;
        }
    }
}

extern "C" void kernel_launch(void* const* d_in, const int* in_sizes, int n_in,
                              void* d_out, int out_size, void* d_ws, size_t ws_size,
                              hipStream_t stream) {
    const float* x       = (const float*)d_in[0];
    const int*   ei_in   = (const int*)d_in[1];
    const int*   ei_out  = (const int*)d_in[2];
    const float* in_Wl0  = (const float*)d_in[3];
    const float* in_bl0  = (const float*)d_in[4];
    const float* in_Wr0  = (const float*)d_in[5];
    const float* out_Wl0 = (const float*)d_in[6];
    const float* out_bl0 = (const float*)d_in[7];
    const float* out_Wr0 = (const float*)d_in[8];
    const float* comb_W0 = (const float*)d_in[9];
    const float* comb_b0 = (const float*)d_in[10];
    const float* in_Wl1  = (const float*)d_in[11];
    const float* in_bl1  = (const float*)d_in[12];
    const float* in_Wr1  = (const float*)d_in[13];
    const float* out_Wl1 = (const float*)d_in[14];
    const float* out_bl1 = (const float*)d_in[15];
    const float* out_Wr1 = (const float*)d_in[16];
    const float* comb_W1 = (const float*)d_in[17];
    const float* comb_b1 = (const float*)d_in[18];
    const float* final_W = (const float*)d_in[19];
    const float* final_b = (const float*)d_in[20];
    float* out = (float*)d_out;

    char* wsb = (char*)d_ws;
    size_t off = 0;
    auto take = [&](size_t sz) -> char* {
        char* p = wsb + off;
        off += (sz + 255) & ~(size_t)255;
        return p;
    };
    float* AGI      = (float*)take((size_t)N_NODES * HALF * 4);
    float* AGO      = (float*)take((size_t)N_NODES * HALF * 4);
    f16* X1h        = (f16*)take((size_t)N_NODES * D * 2);
    f16* P          = (f16*)take((size_t)N_NODES * D * 2);
    int* rp_in      = (int*)take((size_t)(N_NODES + 1) * 4);
    int* rp_out     = (int*)take((size_t)(N_NODES + 1) * 4);
    int* cur_in     = (int*)take((size_t)2 * N_NODES * 4);   // cur_in | cur_out contiguous
    int* cur_out    = cur_in + N_NODES;
    ushortT* csr_in  = (ushortT*)take((size_t)E_EDGES * 2);
    ushortT* csr_out = (ushortT*)take((size_t)E_EDGES * 2);
    f16* Wr0p = (f16*)take(32768);
    f16* Wl1p = (f16*)take(32768);
    f16* Wr1p = (f16*)take(32768);
    f16* Wl0p = (f16*)take(32768);
    f16* cW0p = (f16*)take(65536);
    f16* cW1p = (f16*)take(65536);

    const dim3 blk(256);
    const int pull_grid = (2 * N_NODES * 64) / 256;   // 25000, exact

    // ---- prep: zero counters + pack all weights to fragment order ----
    prep_kernel<<<128, blk, 0, stream>>>(
        cur_in,
        in_Wr0, out_Wr0, in_Wl1, out_Wl1, in_Wr1, out_Wr1, in_Wl0, out_Wl0,
        comb_W0, comb_W1,
        Wr0p, Wl1p, Wr1p, Wl0p, cW0p, cW1p);

    // ---- hist (atomic-bound) + layer-0 P transform (MFMA) co-scheduled ----
    hist_transform_kernel<<<EDGE2_GRID + NODE64_GRID, blk, 0, stream>>>(
        ei_in, ei_out, cur_in, cur_out, x, Wl0p, P);
    scan2_kernel<<<2, 1024, 0, stream>>>(cur_in, cur_out, rp_in, rp_out, N_NODES);
    csr_build2_kernel<<<EDGE2_GRID, blk, 0, stream>>>(ei_in, ei_out, cur_in, cur_out, csr_in, csr_out);

    // ---- layer 0 (fused kernel also emits layer-1 P) ----
    pull_dual_kernel<<<pull_grid, blk, 0, stream>>>(P, rp_in, csr_in, rp_out, csr_out, AGI, AGO);
    fused_mfma_kernel<<<NODE64_GRID, blk, 0, stream>>>(
        x, nullptr, AGI, AGO, Wr0p, in_bl0, out_bl0, cW0p, comb_b0,
        X1h, Wl1p, P, nullptr, nullptr, nullptr);

    // ---- layer 1 (+ fused final head) ----
    pull_dual_kernel<<<pull_grid, blk, 0, stream>>>(P, rp_in, csr_in, rp_out, csr_out, AGI, AGO);
    fused_mfma_kernel<<<NODE64_GRID, blk, 0, stream>>>(
        nullptr, X1h, AGI, AGO, Wr1p, in_bl1, out_bl1, cW1p, comb_b1,
        nullptr, nullptr, nullptr, final_W, final_b, out);
}

// Round 8
// 260.753 us; speedup vs baseline: 21.2240x; 1.2863x over previous
//
#include <hip/hip_runtime.h>
#include <hip/hip_fp16.h>

#define N_NODES 50000
#define D 128
#define HALF 64
#define E_EDGES 625000
#define CAP 64                                       // bucket capacity (max deg ~35)
#define EDGE2_GRID ((2 * E_EDGES + 255) / 256)       // 4883
#define M_BLK 64
#define NODE64_GRID ((N_NODES + M_BLK - 1) / M_BLK)  // 782

typedef unsigned short ushortT;
using f16     = _Float16;
using half8   = __attribute__((ext_vector_type(8))) _Float16;
using half4v  = __attribute__((ext_vector_type(4))) _Float16;
using floatx4 = __attribute__((ext_vector_type(4))) float;

__device__ __forceinline__ int rfl(int v) { return __builtin_amdgcn_readfirstlane(v); }
__device__ __forceinline__ floatx4 mfma16(half8 a, half8 b, floatx4 c) {
    return __builtin_amdgcn_mfma_f32_16x16x32_f16(a, b, c, 0, 0, 0);
}

// A-fragment read from swizzled wave-private LDS tile [16 rows][128 f16].
// Swizzle: 16B chunk cc stored at chunk (cc ^ (row&7)).
__device__ __forceinline__ half8 ldsA(const f16 (*Xw)[D], int lane, int ks) {
    int r = lane & 15;
    int cc = ks * 4 + (lane >> 4);
    return *(const half8*)&Xw[r][((cc ^ (r & 7)) << 3)];
}

// Stage 16 fp32 rows -> fp16 swizzled LDS (wave-private).
__device__ __forceinline__ void stage_f32(f16 (*Xw)[D], const float* __restrict__ X,
                                          int nodeBase, int lane) {
#pragma unroll
    for (int r4 = 0; r4 < 8; ++r4) {
        int s = lane + 64 * r4;            // 512 float4 slots = 16 rows x 32
        int row = s >> 5, c4 = s & 31;
        int nn = nodeBase + row; if (nn > N_NODES - 1) nn = N_NODES - 1;
        float4 v = *(const float4*)(X + (size_t)nn * D + c4 * 4);
        int cc = c4 >> 1;
        half4v pk = { (f16)v.x, (f16)v.y, (f16)v.z, (f16)v.w };
        *(half4v*)&Xw[row][((cc ^ (row & 7)) << 3) + ((c4 & 1) << 2)] = pk;
    }
}

// Stage 16 fp16 rows -> swizzled LDS (16B chunks).
__device__ __forceinline__ void stage_f16(f16 (*Xw)[D], const f16* __restrict__ X,
                                          int nodeBase, int lane) {
#pragma unroll
    for (int r = 0; r < 4; ++r) {
        int s = lane + 64 * r;             // 256 chunk slots = 16 rows x 16
        int row = s >> 4, cc = s & 15;
        int nn = nodeBase + row; if (nn > N_NODES - 1) nn = N_NODES - 1;
        uint4 v = *(const uint4*)(X + (size_t)nn * D + cc * 8);
        *(uint4*)&Xw[row][((cc ^ (row & 7)) << 3)] = v;
    }
}

// GEMM [16 x 128] = LDS-X @ packed-W(K=128), write fp16 result to Pout.
__device__ __forceinline__ void gemm_store_P(const f16 (*Xw)[D], const f16* __restrict__ Wp,
                                             f16* __restrict__ Pout, int nodeBase, int lane) {
    half8 a[4];
#pragma unroll
    for (int ks = 0; ks < 4; ++ks) a[ks] = ldsA(Xw, lane, ks);
#pragma unroll
    for (int ct = 0; ct < 8; ++ct) {
        floatx4 acc = {0.f, 0.f, 0.f, 0.f};
#pragma unroll
        for (int ks = 0; ks < 4; ++ks) {
            half8 b = *(const half8*)(Wp + (((ct * 4 + ks) * 64 + lane) << 3));
            acc = mfma16(a[ks], b, acc);
        }
        int col = ct * 16 + (lane & 15);
#pragma unroll
        for (int i = 0; i < 4; ++i) {
            int nn = nodeBase + (lane >> 4) * 4 + i;
            if (nn < N_NODES) Pout[(size_t)nn * D + col] = (f16)acc[i];
        }
    }
}

// prep: blocks 0..63 zero the 2N count ints; blocks 64..127 pack all six
// weight matrices into MFMA B-fragment order.
__global__ __launch_bounds__(256) void prep_kernel(
    int* __restrict__ cnt,
    const float* iWr0, const float* oWr0, const float* iWl1, const float* oWl1,
    const float* iWr1, const float* oWr1, const float* iWl0, const float* oWl0,
    const float* cW0, const float* cW1,
    f16* Wr0p, f16* Wl1p, f16* Wr1p, f16* Wl0p, f16* cW0p, f16* cW1p)
{
    int b = blockIdx.x;
    if (b < 64) {
        for (int i = b * 256 + threadIdx.x; i < 2 * N_NODES; i += 64 * 256) cnt[i] = 0;
        return;
    }
    b -= 64;
    if (b < 32) {   // dual K=128 packs: 4 weights x 8 blocks
        int w = b >> 3;
        int e = (b & 7) * 256 + threadIdx.x;          // [0, 2048)
        const float* Wa; const float* Wb; f16* dst;
        if (w == 0)      { Wa = iWr0; Wb = oWr0; dst = Wr0p; }
        else if (w == 1) { Wa = iWl1; Wb = oWl1; dst = Wl1p; }
        else if (w == 2) { Wa = iWr1; Wb = oWr1; dst = Wr1p; }
        else             { Wa = iWl0; Wb = oWl0; dst = Wl0p; }
        int lane = e & 63, ks = (e >> 6) & 3, ct = e >> 8;
        int k0 = ks * 32 + ((lane >> 4) << 3), c = ct * 16 + (lane & 15);
        half8 v;
#pragma unroll
        for (int j = 0; j < 8; ++j) {
            int k = k0 + j;
            float f = (c < 64) ? Wa[k * HALF + c] : Wb[k * HALF + (c - 64)];
            v[j] = (f16)f;
        }
        *(half8*)(dst + ((size_t)e << 3)) = v;
        return;
    }
    b -= 32;        // cW K=256 packs: 2 weights x 16 blocks
    {
        int w = b >> 4;
        int e = (b & 15) * 256 + threadIdx.x;         // [0, 4096)
        const float* W = w ? cW1 : cW0;
        f16* dst = w ? cW1p : cW0p;
        int lane = e & 63, ks = (e >> 6) & 7, ct = e >> 9;
        int k0 = ks * 32 + ((lane >> 4) << 3), c = ct * 16 + (lane & 15);
        half8 v;
#pragma unroll
        for (int j = 0; j < 8; ++j) v[j] = (f16)W[(size_t)(k0 + j) * D + c];
        *(half8*)(dst + ((size_t)e << 3)) = v;
    }
}

// Heterogeneous: single-pass bucket scatter of both edge sets (atomic/scatter
// bound) + MFMA transform of layer-0 P (compute-bound). Replaces hist+scan+
// csr_build: pos = atomicAdd(cnt[dst]); bkt[dst*CAP+pos] = src.
__global__ __launch_bounds__(256) void scatter_transform_kernel(
    const int* __restrict__ ei_in, const int* __restrict__ ei_out,
    int* __restrict__ cnt_in, int* __restrict__ cnt_out,
    ushortT* __restrict__ bkt_in, ushortT* __restrict__ bkt_out,
    const float* __restrict__ X, const f16* __restrict__ Wl0p, f16* __restrict__ P)
{
    __shared__ f16 Xh[4][16][D];
    if ((int)blockIdx.x < EDGE2_GRID) {
        int e = blockIdx.x * 256 + threadIdx.x;
        if (e < E_EDGES) {
            int src = ei_in[e], dst = ei_in[E_EDGES + e];
            int pos = atomicAdd(&cnt_in[dst], 1); if (pos > CAP - 1) pos = CAP - 1;
            bkt_in[(size_t)dst * CAP + pos] = (ushortT)src;
        } else if (e < 2 * E_EDGES) {
            int src = ei_out[e - E_EDGES], dst = ei_out[e];
            int pos = atomicAdd(&cnt_out[dst], 1); if (pos > CAP - 1) pos = CAP - 1;
            bkt_out[(size_t)dst * CAP + pos] = (ushortT)src;
        }
        return;
    }
    const int bid = blockIdx.x - EDGE2_GRID;
    const int tid = threadIdx.x, wave = tid >> 6, lane = tid & 63;
    const int nodeBase = bid * M_BLK + wave * 16;
    f16 (*Xw)[D] = Xh[wave];
    stage_f32(Xw, X, nodeBase, lane);
    gemm_store_P(Xw, Wl0p, P, nodeBase, lane);
}

// Mean-aggregate fp16 64-wide halves of P over fixed-cap buckets.
// One wave per (node, dir); 8 edges in flight (sub = lane>>3 picks edge,
// c = lane&7 picks 16B half8 chunk). fp32 accumulate, fp16 mean out.
__global__ __launch_bounds__(256) void pull_dual_kernel(
    const f16* __restrict__ P,
    const int* __restrict__ cnt_in, const ushortT* __restrict__ bkt_in,
    const int* __restrict__ cnt_out, const ushortT* __restrict__ bkt_out,
    f16* __restrict__ agg_in, f16* __restrict__ agg_out)
{
    int gid = blockIdx.x * blockDim.x + threadIdx.x;
    int wid = gid >> 6;
    const int lane = gid & 63;
    const int sub = lane >> 3;
    const int c = lane & 7;
    const int* cnt; const ushortT* bkt; f16* agg; int coloff;
    if (wid < N_NODES) { cnt = cnt_in; bkt = bkt_in; agg = agg_in; coloff = 0; }
    else { wid -= N_NODES; cnt = cnt_out; bkt = bkt_out; agg = agg_out; coloff = HALF; }
    const int node = rfl(wid);
    int deg = rfl(cnt[node]); if (deg > CAP) deg = CAP;
    const ushortT* row = bkt + (size_t)node * CAP;
    const f16* Pb = P + coloff + c * 8;
    float acc[8];
#pragma unroll
    for (int t = 0; t < 8; ++t) acc[t] = 0.0f;
    for (int j = 0; j < deg; j += 8) {
        int jc = j + sub;
        int idx = row[jc < deg ? jc : deg - 1];
        float m = (jc < deg) ? 1.0f : 0.0f;
        half8 v = *(const half8*)(Pb + (size_t)idx * D);
#pragma unroll
        for (int t = 0; t < 8; ++t) acc[t] = fmaf(m, (float)v[t], acc[t]);
    }
#pragma unroll
    for (int t = 0; t < 8; ++t) {
        acc[t] += __shfl_xor(acc[t], 8, 64);
        acc[t] += __shfl_xor(acc[t], 16, 64);
        acc[t] += __shfl_xor(acc[t], 32, 64);
    }
    if (sub == 0) {
        float inv = 1.0f / fmaxf((float)deg, 1.0f);
        half8 o;
#pragma unroll
        for (int t = 0; t < 8; ++t) o[t] = (f16)(acc[t] * inv);
        *(half8*)(agg + (size_t)node * HALF + c * 8) = o;
    }
}

// Fused MFMA SAGE layer: conv (X@[Wr_in|Wr_out] + agg + bias, relu) -> Hh LDS
// -> combine ([X|H]@cW + cb, relu) -> either {write X1 fp16 + next-layer P}
// or {final head}. All LDS wave-private (no barriers).
__global__ __launch_bounds__(256) void fused_mfma_kernel(
    const float* __restrict__ Xf, const f16* __restrict__ X16,
    const f16* __restrict__ AGI, const f16* __restrict__ AGO,
    const f16* __restrict__ Wrp, const float* __restrict__ bl_in, const float* __restrict__ bl_out,
    const f16* __restrict__ cWp, const float* __restrict__ cb,
    f16* __restrict__ Xout16,
    const f16* __restrict__ Wlnp, f16* __restrict__ Pout,
    const float* __restrict__ fW, const float* __restrict__ fb, float* __restrict__ outv)
{
    __shared__ f16 Xh[4][16][D];
    __shared__ f16 Hh[4][16][D];
    const int tid = threadIdx.x, wave = tid >> 6, lane = tid & 63;
    const int nodeBase = blockIdx.x * M_BLK + wave * 16;
    f16 (*Xw)[D] = Xh[wave];
    f16 (*Hw)[D] = Hh[wave];
    const int colq = lane & 15;
    const int rq = lane >> 4;

    if (Xf) stage_f32(Xw, Xf, nodeBase, lane);
    else    stage_f16(Xw, X16, nodeBase, lane);

    half8 aX[4];
#pragma unroll
    for (int ks = 0; ks < 4; ++ks) aX[ks] = ldsA(Xw, lane, ks);

    // ---- conv: tiles ct<4 -> h_in cols, ct>=4 -> h_out cols ----
#pragma unroll
    for (int ct = 0; ct < 8; ++ct) {
        floatx4 acc = {0.f, 0.f, 0.f, 0.f};
#pragma unroll
        for (int ks = 0; ks < 4; ++ks) {
            half8 b = *(const half8*)(Wrp + (((ct * 4 + ks) * 64 + lane) << 3));
            acc = mfma16(aX[ks], b, acc);
        }
        int c64 = (ct & 3) * 16 + colq;
        const f16* AG = (ct < 4) ? AGI : AGO;
        float bl = (ct < 4) ? bl_in[c64] : bl_out[c64];
        int colg = ct * 16 + colq;
        int cc = colg >> 3;
#pragma unroll
        for (int i = 0; i < 4; ++i) {
            int r16 = rq * 4 + i;
            int nn = nodeBase + r16; if (nn > N_NODES - 1) nn = N_NODES - 1;
            float h = acc[i] + (float)AG[(size_t)nn * HALF + c64] + bl;
            Hw[r16][((cc ^ (r16 & 7)) << 3) + (colg & 7)] = (f16)fmaxf(h, 0.f);
        }
    }

    // ---- combine: [X | H] @ cW + cb ----
    floatx4 acc2[8];
#pragma unroll
    for (int ct = 0; ct < 8; ++ct) {
        float cbv = cb[ct * 16 + colq];
        floatx4 t = {cbv, cbv, cbv, cbv};
#pragma unroll
        for (int ks = 0; ks < 4; ++ks) {
            half8 b = *(const half8*)(cWp + (((ct * 8 + ks) * 64 + lane) << 3));
            t = mfma16(aX[ks], b, t);
        }
        acc2[ct] = t;
    }
    half8 aH[4];
#pragma unroll
    for (int ks = 0; ks < 4; ++ks) aH[ks] = ldsA(Hw, lane, ks);
#pragma unroll
    for (int ct = 0; ct < 8; ++ct) {
#pragma unroll
        for (int ks = 0; ks < 4; ++ks) {
            half8 b = *(const half8*)(cWp + (((ct * 8 + 4 + ks) * 64 + lane) << 3));
            acc2[ct] = mfma16(aH[ks], b, acc2[ct]);
        }
    }

    if (fW == nullptr) {
        // x_new: write fp16 global + restage into Xh for next-layer transform
#pragma unroll
        for (int ct = 0; ct < 8; ++ct) {
            int colg = ct * 16 + colq;
            int cc = colg >> 3;
#pragma unroll
            for (int i = 0; i < 4; ++i) {
                int r16 = rq * 4 + i;
                int nn = nodeBase + r16;
                f16 hv = (f16)fmaxf(acc2[ct][i], 0.f);
                if (nn < N_NODES) Xout16[(size_t)nn * D + colg] = hv;
                Xw[r16][((cc ^ (r16 & 7)) << 3) + (colg & 7)] = hv;
            }
        }
        gemm_store_P(Xw, Wlnp, Pout, nodeBase, lane);
    } else {
        // final head: out[node] = sum_c relu(X2[node][c]) * fW[c] + fb
        float fs0 = 0, fs1 = 0, fs2 = 0, fs3 = 0;
#pragma unroll
        for (int ct = 0; ct < 8; ++ct) {
            float fwv = fW[ct * 16 + colq];
            fs0 = fmaf(fmaxf(acc2[ct][0], 0.f), fwv, fs0);
            fs1 = fmaf(fmaxf(acc2[ct][1], 0.f), fwv, fs1);
            fs2 = fmaf(fmaxf(acc2[ct][2], 0.f), fwv, fs2);
            fs3 = fmaf(fmaxf(acc2[ct][3], 0.f), fwv, fs3);
        }
#pragma unroll
        for (int off = 1; off < 16; off <<= 1) {
            fs0 += __shfl_xor(fs0, off, 64);
            fs1 += __shfl_xor(fs1, off, 64);
            fs2 += __shfl_xor(fs2, off, 64);
            fs3 += __shfl_xor(fs3, off, 64);
        }
        if (colq == 0) {
            float fbv = fb[0];
            int nb = nodeBase + rq * 4;
            if (nb + 0 < N_NODES) outv[nb + 0] = fs0 + fbv;
            if (nb + 1 < N_NODES) outv[nb + 1] = fs1 + fbv;
            if (nb + 2 < N_NODES) outv[nb + 2] = fs2 + fbv;
            if (nb + 3 < N_NODES) outv[nb + 3] = fs3 + fbv;
        }
    }
}

extern "C" void kernel_launch(void* const* d_in, const int* in_sizes, int n_in,
                              void* d_out, int out_size, void* d_ws, size_t ws_size,
                              hipStream_t stream) {
    const float* x       = (const float*)d_in[0];
    const int*   ei_in   = (const int*)d_in[1];
    const int*   ei_out  = (const int*)d_in[2];
    const float* in_Wl0  = (const float*)d_in[3];
    const float* in_bl0  = (const float*)d_in[4];
    const float* in_Wr0  = (const float*)d_in[5];
    const float* out_Wl0 = (const float*)d_in[6];
    const float* out_bl0 = (const float*)d_in[7];
    const float* out_Wr0 = (const float*)d_in[8];
    const float* comb_W0 = (const float*)d_in[9];
    const float* comb_b0 = (const float*)d_in[10];
    const float* in_Wl1  = (const float*)d_in[11];
    const float* in_bl1  = (const float*)d_in[12];
    const float* in_Wr1  = (const float*)d_in[13];
    const float* out_Wl1 = (const float*)d_in[14];
    const float* out_bl1 = (const float*)d_in[15];
    const float* out_Wr1 = (const float*)d_in[16];
    const float* comb_W1 = (const float*)d_in[17];
    const float* comb_b1 = (const float*)d_in[18];
    const float* final_W = (const float*)d_in[19];
    const float* final_b = (const float*)d_in[20];
    float* out = (float*)d_out;

    char* wsb = (char*)d_ws;
    size_t off = 0;
    auto take = [&](size_t sz) -> char* {
        char* p = wsb + off;
        off += (sz + 255) & ~(size_t)255;
        return p;
    };
    f16* AGI       = (f16*)take((size_t)N_NODES * HALF * 2);
    f16* AGO       = (f16*)take((size_t)N_NODES * HALF * 2);
    f16* X1h       = (f16*)take((size_t)N_NODES * D * 2);
    f16* P         = (f16*)take((size_t)N_NODES * D * 2);
    int* cnt_in    = (int*)take((size_t)2 * N_NODES * 4);   // cnt_in | cnt_out contiguous
    int* cnt_out   = cnt_in + N_NODES;
    ushortT* bkt_in  = (ushortT*)take((size_t)N_NODES * CAP * 2);
    ushortT* bkt_out = (ushortT*)take((size_t)N_NODES * CAP * 2);
    f16* Wr0p = (f16*)take(32768);
    f16* Wl1p = (f16*)take(32768);
    f16* Wr1p = (f16*)take(32768);
    f16* Wl0p = (f16*)take(32768);
    f16* cW0p = (f16*)take(65536);
    f16* cW1p = (f16*)take(65536);

    const dim3 blk(256);
    const int pull_grid = (2 * N_NODES * 64) / 256;   // 25000, exact

    // ---- prep: zero counters + pack all weights to fragment order ----
    prep_kernel<<<128, blk, 0, stream>>>(
        cnt_in,
        in_Wr0, out_Wr0, in_Wl1, out_Wl1, in_Wr1, out_Wr1, in_Wl0, out_Wl0,
        comb_W0, comb_W1,
        Wr0p, Wl1p, Wr1p, Wl0p, cW0p, cW1p);

    // ---- bucket scatter (atomic-bound) + layer-0 P transform co-scheduled ----
    scatter_transform_kernel<<<EDGE2_GRID + NODE64_GRID, blk, 0, stream>>>(
        ei_in, ei_out, cnt_in, cnt_out, bkt_in, bkt_out, x, Wl0p, P);

    // ---- layer 0 (fused kernel also emits layer-1 P) ----
    pull_dual_kernel<<<pull_grid, blk, 0, stream>>>(P, cnt_in, bkt_in, cnt_out, bkt_out, AGI, AGO);
    fused_mfma_kernel<<<NODE64_GRID, blk, 0, stream>>>(
        x, nullptr, AGI, AGO, Wr0p, in_bl0, out_bl0, cW0p, comb_b0,
        X1h, Wl1p, P, nullptr, nullptr, nullptr);

    // ---- layer 1 (+ fused final head) ----
    pull_dual_kernel<<<pull_grid, blk, 0, stream>>>(P, cnt_in, bkt_in, cnt_out, bkt_out, AGI, AGO);
    fused_mfma_kernel<<<NODE64_GRID, blk, 0, stream>>>(
        nullptr, X1h, AGI, AGO, Wr1p, in_bl1, out_bl1, cW1p, comb_b1,
        nullptr, nullptr, nullptr, final_W, final_b, out);
}

// Round 9
// 182.045 us; speedup vs baseline: 30.4003x; 1.4324x over previous
//
#include <hip/hip_runtime.h>
#include <hip/hip_fp16.h>

#define N_NODES 50000
#define D 128
#define HALF 64
#define E_EDGES 625000
#define CAP 64                                       // bucket capacity (max deg ~35)
#define M_BLK 64
#define NODE64_GRID ((N_NODES + M_BLK - 1) / M_BLK)  // 782

// --- radix partition geometry ---
#define NBINS 196                                    // bins of 256 nodes: bin = dst>>8
#define BIN_NODES 256
#define BINCAP 4096                                  // per-bin capacity (mean ~3200, +14 sigma)
#define GA 98                                        // partition blocks per edge set
#define CHUNK ((E_EDGES + GA - 1) / GA)              // 6379 edges per block
#define PARTA_GRID (2 * GA)                          // 196

typedef unsigned short ushortT;
typedef unsigned int uintT;
using f16     = _Float16;
using half8   = __attribute__((ext_vector_type(8))) _Float16;
using half4v  = __attribute__((ext_vector_type(4))) _Float16;
using floatx4 = __attribute__((ext_vector_type(4))) float;

__device__ __forceinline__ int rfl(int v) { return __builtin_amdgcn_readfirstlane(v); }
__device__ __forceinline__ floatx4 mfma16(half8 a, half8 b, floatx4 c) {
    return __builtin_amdgcn_mfma_f32_16x16x32_f16(a, b, c, 0, 0, 0);
}

// A-fragment read from swizzled wave-private LDS tile [16 rows][128 f16].
// Swizzle: 16B chunk cc stored at chunk (cc ^ (row&7)).
__device__ __forceinline__ half8 ldsA(const f16 (*Xw)[D], int lane, int ks) {
    int r = lane & 15;
    int cc = ks * 4 + (lane >> 4);
    return *(const half8*)&Xw[r][((cc ^ (r & 7)) << 3)];
}

// Stage 16 fp32 rows -> fp16 swizzled LDS (wave-private).
__device__ __forceinline__ void stage_f32(f16 (*Xw)[D], const float* __restrict__ X,
                                          int nodeBase, int lane) {
#pragma unroll
    for (int r4 = 0; r4 < 8; ++r4) {
        int s = lane + 64 * r4;            // 512 float4 slots = 16 rows x 32
        int row = s >> 5, c4 = s & 31;
        int nn = nodeBase + row; if (nn > N_NODES - 1) nn = N_NODES - 1;
        float4 v = *(const float4*)(X + (size_t)nn * D + c4 * 4);
        int cc = c4 >> 1;
        half4v pk = { (f16)v.x, (f16)v.y, (f16)v.z, (f16)v.w };
        *(half4v*)&Xw[row][((cc ^ (row & 7)) << 3) + ((c4 & 1) << 2)] = pk;
    }
}

// Stage 16 fp16 rows -> swizzled LDS (16B chunks).
__device__ __forceinline__ void stage_f16(f16 (*Xw)[D], const f16* __restrict__ X,
                                          int nodeBase, int lane) {
#pragma unroll
    for (int r = 0; r < 4; ++r) {
        int s = lane + 64 * r;             // 256 chunk slots = 16 rows x 16
        int row = s >> 4, cc = s & 15;
        int nn = nodeBase + row; if (nn > N_NODES - 1) nn = N_NODES - 1;
        uint4 v = *(const uint4*)(X + (size_t)nn * D + cc * 8);
        *(uint4*)&Xw[row][((cc ^ (row & 7)) << 3)] = v;
    }
}

// GEMM [16 x 128] = LDS-X @ packed-W(K=128), write fp16 result to Pout.
__device__ __forceinline__ void gemm_store_P(const f16 (*Xw)[D], const f16* __restrict__ Wp,
                                             f16* __restrict__ Pout, int nodeBase, int lane) {
    half8 a[4];
#pragma unroll
    for (int ks = 0; ks < 4; ++ks) a[ks] = ldsA(Xw, lane, ks);
#pragma unroll
    for (int ct = 0; ct < 8; ++ct) {
        floatx4 acc = {0.f, 0.f, 0.f, 0.f};
#pragma unroll
        for (int ks = 0; ks < 4; ++ks) {
            half8 b = *(const half8*)(Wp + (((ct * 4 + ks) * 64 + lane) << 3));
            acc = mfma16(a[ks], b, acc);
        }
        int col = ct * 16 + (lane & 15);
#pragma unroll
        for (int i = 0; i < 4; ++i) {
            int nn = nodeBase + (lane >> 4) * 4 + i;
            if (nn < N_NODES) Pout[(size_t)nn * D + col] = (f16)acc[i];
        }
    }
}

// prep: blocks 0..63 zero the 2*NBINS bin cursors; blocks 64..127 pack all six
// weight matrices into MFMA B-fragment order.
__global__ __launch_bounds__(256) void prep_kernel(
    int* __restrict__ gcur,
    const float* iWr0, const float* oWr0, const float* iWl1, const float* oWl1,
    const float* iWr1, const float* oWr1, const float* iWl0, const float* oWl0,
    const float* cW0, const float* cW1,
    f16* Wr0p, f16* Wl1p, f16* Wr1p, f16* Wl0p, f16* cW0p, f16* cW1p)
{
    int b = blockIdx.x;
    if (b < 64) {
        for (int i = b * 256 + threadIdx.x; i < 2 * NBINS; i += 64 * 256) gcur[i] = 0;
        return;
    }
    b -= 64;
    if (b < 32) {   // dual K=128 packs: 4 weights x 8 blocks
        int w = b >> 3;
        int e = (b & 7) * 256 + threadIdx.x;          // [0, 2048)
        const float* Wa; const float* Wb; f16* dst;
        if (w == 0)      { Wa = iWr0; Wb = oWr0; dst = Wr0p; }
        else if (w == 1) { Wa = iWl1; Wb = oWl1; dst = Wl1p; }
        else if (w == 2) { Wa = iWr1; Wb = oWr1; dst = Wr1p; }
        else             { Wa = iWl0; Wb = oWl0; dst = Wl0p; }
        int lane = e & 63, ks = (e >> 6) & 3, ct = e >> 8;
        int k0 = ks * 32 + ((lane >> 4) << 3), c = ct * 16 + (lane & 15);
        half8 v;
#pragma unroll
        for (int j = 0; j < 8; ++j) {
            int k = k0 + j;
            float f = (c < 64) ? Wa[k * HALF + c] : Wb[k * HALF + (c - 64)];
            v[j] = (f16)f;
        }
        *(half8*)(dst + ((size_t)e << 3)) = v;
        return;
    }
    b -= 32;        // cW K=256 packs: 2 weights x 16 blocks
    {
        int w = b >> 4;
        int e = (b & 15) * 256 + threadIdx.x;         // [0, 4096)
        const float* W = w ? cW1 : cW0;
        f16* dst = w ? cW1p : cW0p;
        int lane = e & 63, ks = (e >> 6) & 7, ct = e >> 9;
        int k0 = ks * 32 + ((lane >> 4) << 3), c = ct * 16 + (lane & 15);
        half8 v;
#pragma unroll
        for (int j = 0; j < 8; ++j) v[j] = (f16)W[(size_t)(k0 + j) * D + c];
        *(half8*)(dst + ((size_t)e << 3)) = v;
    }
}

// Heterogeneous launch:
//  blocks [0, PARTA_GRID): phase-A radix partition of one edge-set chunk —
//    LDS-staged edges, LDS histogram of 196 bins, ONE global atomic per
//    (block,bin) to reserve a range, then near-coalesced packed writes.
//  blocks [PARTA_GRID, +NODE64_GRID): MFMA transform P = X @ Wl0 (fp16).
__global__ __launch_bounds__(256) void part_transform_kernel(
    const int* __restrict__ ei_in, const int* __restrict__ ei_out,
    int* __restrict__ gcur, uintT* __restrict__ part,
    const float* __restrict__ X, const f16* __restrict__ Wl0p, f16* __restrict__ P)
{
    __shared__ __align__(16) char lraw[28032];
    const int tid = threadIdx.x;
    if ((int)blockIdx.x < PARTA_GRID) {
        uintT* le   = (uintT*)lraw;                       // 6400 x 4B
        int* cnt_l  = (int*)(lraw + 25600);               // 196
        int* base_l = cnt_l + NBINS;
        int* run_l  = base_l + NBINS;
        const int set = (int)blockIdx.x >= GA;
        const int b = blockIdx.x - (set ? GA : 0);
        const int* ei = set ? ei_out : ei_in;
        const int e0 = b * CHUNK;
        int n = E_EDGES - e0; if (n > CHUNK) n = CHUNK; if (n < 0) n = 0;
        for (int j = tid; j < n; j += 256) {
            int src = ei[e0 + j];
            int dst = ei[E_EDGES + e0 + j];
            le[j] = ((uintT)dst << 16) | (uintT)src;      // both < 2^16
        }
        for (int j = tid; j < NBINS; j += 256) cnt_l[j] = 0;
        __syncthreads();
        for (int j = tid; j < n; j += 256) atomicAdd(&cnt_l[le[j] >> 24], 1);  // bin = dst>>8
        __syncthreads();
        for (int j = tid; j < NBINS; j += 256) {
            int c = cnt_l[j];
            base_l[j] = c ? atomicAdd(&gcur[set * NBINS + j], c) : 0;
            run_l[j] = 0;
        }
        __syncthreads();
        uintT* pbase = part + (size_t)set * NBINS * BINCAP;
        for (int j = tid; j < n; j += 256) {
            uintT v = le[j];
            int bin = v >> 24;
            int pos = base_l[bin] + atomicAdd(&run_l[bin], 1);
            if (pos < BINCAP) pbase[(size_t)bin * BINCAP + pos] = v;
        }
        return;
    }
    // ---- transform part ----
    f16 (*Xh)[16][D] = (f16(*)[16][D])lraw;               // 4 x 16 x 128 f16 = 16 KB
    const int bid = blockIdx.x - PARTA_GRID;
    const int wave = tid >> 6, lane = tid & 63;
    const int nodeBase = bid * M_BLK + wave * 16;
    f16 (*Xw)[D] = Xh[wave];
    stage_f32(Xw, X, nodeBase, lane);
    gemm_store_P(Xw, Wl0p, P, nodeBase, lane);
}

// Phase B: one block per (bin, set). Build the 256-node bucket tile in LDS
// (LDS atomics only), then write counts + 32 KB tile fully coalesced.
// Output layout identical to the previous cnt/bkt arrays.
__global__ __launch_bounds__(256) void bucket_build_kernel(
    const uintT* __restrict__ part, const int* __restrict__ gcur,
    int* __restrict__ cnt_in, int* __restrict__ cnt_out,
    ushortT* __restrict__ bkt_in, ushortT* __restrict__ bkt_out)
{
    __shared__ ushortT bk[BIN_NODES * CAP];   // 32 KB
    __shared__ int cl[BIN_NODES];
    const int tid = threadIdx.x;
    const int set = (int)blockIdx.x >= NBINS;
    const int bin = blockIdx.x - (set ? NBINS : 0);
    int total = gcur[set * NBINS + bin]; if (total > BINCAP) total = BINCAP;
    const uintT* pb = part + ((size_t)set * NBINS + bin) * BINCAP;
    cl[tid] = 0;
    __syncthreads();
    for (int j = tid; j < total; j += 256) {
        uintT v = pb[j];
        int loc = (v >> 16) & 255;
        int pos = atomicAdd(&cl[loc], 1);
        if (pos < CAP) bk[loc * CAP + pos] = (ushortT)(v & 0xFFFF);
    }
    __syncthreads();
    const int node0 = bin * BIN_NODES;
    int* cnt = set ? cnt_out : cnt_in;
    ushortT* bkt = set ? bkt_out : bkt_in;
    if (node0 + tid < N_NODES) cnt[node0 + tid] = cl[tid];
    const uint4* s4 = (const uint4*)bk;
    uint4* d4 = (uint4*)(bkt + (size_t)node0 * CAP);
    int lim = N_NODES - node0; if (lim > BIN_NODES) lim = BIN_NODES;
    lim = lim * (CAP / 8);                   // uint4 slots (8 ushorts each)
    for (int j = tid; j < lim; j += 256) d4[j] = s4[j];
}

// Mean-aggregate fp16 64-wide halves of P over fixed-cap buckets.
// One wave per (node, dir); 8 edges in flight (sub = lane>>3 picks edge,
// c = lane&7 picks 16B half8 chunk). fp32 accumulate, fp16 mean out.
__global__ __launch_bounds__(256) void pull_dual_kernel(
    const f16* __restrict__ P,
    const int* __restrict__ cnt_in, const ushortT* __restrict__ bkt_in,
    const int* __restrict__ cnt_out, const ushortT* __restrict__ bkt_out,
    f16* __restrict__ agg_in, f16* __restrict__ agg_out)
{
    int gid = blockIdx.x * blockDim.x + threadIdx.x;
    int wid = gid >> 6;
    const int lane = gid & 63;
    const int sub = lane >> 3;
    const int c = lane & 7;
    const int* cnt; const ushortT* bkt; f16* agg; int coloff;
    if (wid < N_NODES) { cnt = cnt_in; bkt = bkt_in; agg = agg_in; coloff = 0; }
    else { wid -= N_NODES; cnt = cnt_out; bkt = bkt_out; agg = agg_out; coloff = HALF; }
    const int node = rfl(wid);
    int deg = rfl(cnt[node]); if (deg > CAP) deg = CAP;
    const ushortT* row = bkt + (size_t)node * CAP;
    const f16* Pb = P + coloff + c * 8;
    float acc[8];
#pragma unroll
    for (int t = 0; t < 8; ++t) acc[t] = 0.0f;
    for (int j = 0; j < deg; j += 8) {
        int jc = j + sub;
        int idx = row[jc < deg ? jc : deg - 1];
        float m = (jc < deg) ? 1.0f : 0.0f;
        half8 v = *(const half8*)(Pb + (size_t)idx * D);
#pragma unroll
        for (int t = 0; t < 8; ++t) acc[t] = fmaf(m, (float)v[t], acc[t]);
    }
#pragma unroll
    for (int t = 0; t < 8; ++t) {
        acc[t] += __shfl_xor(acc[t], 8, 64);
        acc[t] += __shfl_xor(acc[t], 16, 64);
        acc[t] += __shfl_xor(acc[t], 32, 64);
    }
    if (sub == 0) {
        float inv = 1.0f / fmaxf((float)deg, 1.0f);
        half8 o;
#pragma unroll
        for (int t = 0; t < 8; ++t) o[t] = (f16)(acc[t] * inv);
        *(half8*)(agg + (size_t)node * HALF + c * 8) = o;
    }
}

// Fused MFMA SAGE layer: conv (X@[Wr_in|Wr_out] + agg + bias, relu) -> Hh LDS
// -> combine ([X|H]@cW + cb, relu) -> either {write X1 fp16 + next-layer P}
// or {final head}. All LDS wave-private (no barriers).
__global__ __launch_bounds__(256) void fused_mfma_kernel(
    const float* __restrict__ Xf, const f16* __restrict__ X16,
    const f16* __restrict__ AGI, const f16* __restrict__ AGO,
    const f16* __restrict__ Wrp, const float* __restrict__ bl_in, const float* __restrict__ bl_out,
    const f16* __restrict__ cWp, const float* __restrict__ cb,
    f16* __restrict__ Xout16,
    const f16* __restrict__ Wlnp, f16* __restrict__ Pout,
    const float* __restrict__ fW, const float* __restrict__ fb, float* __restrict__ outv)
{
    __shared__ f16 Xh[4][16][D];
    __shared__ f16 Hh[4][16][D];
    const int tid = threadIdx.x, wave = tid >> 6, lane = tid & 63;
    const int nodeBase = blockIdx.x * M_BLK + wave * 16;
    f16 (*Xw)[D] = Xh[wave];
    f16 (*Hw)[D] = Hh[wave];
    const int colq = lane & 15;
    const int rq = lane >> 4;

    if (Xf) stage_f32(Xw, Xf, nodeBase, lane);
    else    stage_f16(Xw, X16, nodeBase, lane);

    half8 aX[4];
#pragma unroll
    for (int ks = 0; ks < 4; ++ks) aX[ks] = ldsA(Xw, lane, ks);

    // ---- conv: tiles ct<4 -> h_in cols, ct>=4 -> h_out cols ----
#pragma unroll
    for (int ct = 0; ct < 8; ++ct) {
        floatx4 acc = {0.f, 0.f, 0.f, 0.f};
#pragma unroll
        for (int ks = 0; ks < 4; ++ks) {
            half8 b = *(const half8*)(Wrp + (((ct * 4 + ks) * 64 + lane) << 3));
            acc = mfma16(aX[ks], b, acc);
        }
        int c64 = (ct & 3) * 16 + colq;
        const f16* AG = (ct < 4) ? AGI : AGO;
        float bl = (ct < 4) ? bl_in[c64] : bl_out[c64];
        int colg = ct * 16 + colq;
        int cc = colg >> 3;
#pragma unroll
        for (int i = 0; i < 4; ++i) {
            int r16 = rq * 4 + i;
            int nn = nodeBase + r16; if (nn > N_NODES - 1) nn = N_NODES - 1;
            float h = acc[i] + (float)AG[(size_t)nn * HALF + c64] + bl;
            Hw[r16][((cc ^ (r16 & 7)) << 3) + (colg & 7)] = (f16)fmaxf(h, 0.f);
        }
    }

    // ---- combine: [X | H] @ cW + cb ----
    floatx4 acc2[8];
#pragma unroll
    for (int ct = 0; ct < 8; ++ct) {
        float cbv = cb[ct * 16 + colq];
        floatx4 t = {cbv, cbv, cbv, cbv};
#pragma unroll
        for (int ks = 0; ks < 4; ++ks) {
            half8 b = *(const half8*)(cWp + (((ct * 8 + ks) * 64 + lane) << 3));
            t = mfma16(aX[ks], b, t);
        }
        acc2[ct] = t;
    }
    half8 aH[4];
#pragma unroll
    for (int ks = 0; ks < 4; ++ks) aH[ks] = ldsA(Hw, lane, ks);
#pragma unroll
    for (int ct = 0; ct < 8; ++ct) {
#pragma unroll
        for (int ks = 0; ks < 4; ++ks) {
            half8 b = *(const half8*)(cWp + (((ct * 8 + 4 + ks) * 64 + lane) << 3));
            acc2[ct] = mfma16(aH[ks], b, acc2[ct]);
        }
    }

    if (fW == nullptr) {
        // x_new: write fp16 global + restage into Xh for next-layer transform
#pragma unroll
        for (int ct = 0; ct < 8; ++ct) {
            int colg = ct * 16 + colq;
            int cc = colg >> 3;
#pragma unroll
            for (int i = 0; i < 4; ++i) {
                int r16 = rq * 4 + i;
                int nn = nodeBase + r16;
                f16 hv = (f16)fmaxf(acc2[ct][i], 0.f);
                if (nn < N_NODES) Xout16[(size_t)nn * D + colg] = hv;
                Xw[r16][((cc ^ (r16 & 7)) << 3) + (colg & 7)] = hv;
            }
        }
        gemm_store_P(Xw, Wlnp, Pout, nodeBase, lane);
    } else {
        // final head: out[node] = sum_c relu(X2[node][c]) * fW[c] + fb
        float fs0 = 0, fs1 = 0, fs2 = 0, fs3 = 0;
#pragma unroll
        for (int ct = 0; ct < 8; ++ct) {
            float fwv = fW[ct * 16 + colq];
            fs0 = fmaf(fmaxf(acc2[ct][0], 0.f), fwv, fs0);
            fs1 = fmaf(fmaxf(acc2[ct][1], 0.f), fwv, fs1);
            fs2 = fmaf(fmaxf(acc2[ct][2], 0.f), fwv, fs2);
            fs3 = fmaf(fmaxf(acc2[ct][3], 0.f), fwv, fs3);
        }
#pragma unroll
        for (int off = 1; off < 16; off <<= 1) {
            fs0 += __shfl_xor(fs0, off, 64);
            fs1 += __shfl_xor(fs1, off, 64);
            fs2 += __shfl_xor(fs2, off, 64);
            fs3 += __shfl_xor(fs3, off, 64);
        }
        if (colq == 0) {
            float fbv = fb[0];
            int nb = nodeBase + rq * 4;
            if (nb + 0 < N_NODES) outv[nb + 0] = fs0 + fbv;
            if (nb + 1 < N_NODES) outv[nb + 1] = fs1 + fbv;
            if (nb + 2 < N_NODES) outv[nb + 2] = fs2 + fbv;
            if (nb + 3 < N_NODES) outv[nb + 3] = fs3 + fbv;
        }
    }
}

extern "C" void kernel_launch(void* const* d_in, const int* in_sizes, int n_in,
                              void* d_out, int out_size, void* d_ws, size_t ws_size,
                              hipStream_t stream) {
    const float* x       = (const float*)d_in[0];
    const int*   ei_in   = (const int*)d_in[1];
    const int*   ei_out  = (const int*)d_in[2];
    const float* in_Wl0  = (const float*)d_in[3];
    const float* in_bl0  = (const float*)d_in[4];
    const float* in_Wr0  = (const float*)d_in[5];
    const float* out_Wl0 = (const float*)d_in[6];
    const float* out_bl0 = (const float*)d_in[7];
    const float* out_Wr0 = (const float*)d_in[8];
    const float* comb_W0 = (const float*)d_in[9];
    const float* comb_b0 = (const float*)d_in[10];
    const float* in_Wl1  = (const float*)d_in[11];
    const float* in_bl1  = (const float*)d_in[12];
    const float* in_Wr1  = (const float*)d_in[13];
    const float* out_Wl1 = (const float*)d_in[14];
    const float* out_bl1 = (const float*)d_in[15];
    const float* out_Wr1 = (const float*)d_in[16];
    const float* comb_W1 = (const float*)d_in[17];
    const float* comb_b1 = (const float*)d_in[18];
    const float* final_W = (const float*)d_in[19];
    const float* final_b = (const float*)d_in[20];
    float* out = (float*)d_out;

    char* wsb = (char*)d_ws;
    size_t off = 0;
    auto take = [&](size_t sz) -> char* {
        char* p = wsb + off;
        off += (sz + 255) & ~(size_t)255;
        return p;
    };
    f16* AGI       = (f16*)take((size_t)N_NODES * HALF * 2);
    f16* AGO       = (f16*)take((size_t)N_NODES * HALF * 2);
    f16* X1h       = (f16*)take((size_t)N_NODES * D * 2);
    f16* P         = (f16*)take((size_t)N_NODES * D * 2);
    int* cnt_in    = (int*)take((size_t)2 * N_NODES * 4);   // cnt_in | cnt_out contiguous
    int* cnt_out   = cnt_in + N_NODES;
    ushortT* bkt_in  = (ushortT*)take((size_t)N_NODES * CAP * 2);
    ushortT* bkt_out = (ushortT*)take((size_t)N_NODES * CAP * 2);
    int* gcur      = (int*)take((size_t)2 * NBINS * 4);
    uintT* part    = (uintT*)take((size_t)2 * NBINS * BINCAP * 4);   // 6.4 MB
    f16* Wr0p = (f16*)take(32768);
    f16* Wl1p = (f16*)take(32768);
    f16* Wr1p = (f16*)take(32768);
    f16* Wl0p = (f16*)take(32768);
    f16* cW0p = (f16*)take(65536);
    f16* cW1p = (f16*)take(65536);

    const dim3 blk(256);
    const int pull_grid = (2 * N_NODES * 64) / 256;   // 25000, exact

    // ---- prep: zero bin cursors + pack all weights to fragment order ----
    prep_kernel<<<128, blk, 0, stream>>>(
        gcur,
        in_Wr0, out_Wr0, in_Wl1, out_Wl1, in_Wr1, out_Wr1, in_Wl0, out_Wl0,
        comb_W0, comb_W1,
        Wr0p, Wl1p, Wr1p, Wl0p, cW0p, cW1p);

    // ---- phase-A radix partition (LDS-privatized) + layer-0 P transform ----
    part_transform_kernel<<<PARTA_GRID + NODE64_GRID, blk, 0, stream>>>(
        ei_in, ei_out, gcur, part, x, Wl0p, P);

    // ---- phase-B: coalesced bucket build from partitioned edges ----
    bucket_build_kernel<<<2 * NBINS, blk, 0, stream>>>(
        part, gcur, cnt_in, cnt_out, bkt_in, bkt_out);

    // ---- layer 0 (fused kernel also emits layer-1 P) ----
    pull_dual_kernel<<<pull_grid, blk, 0, stream>>>(P, cnt_in, bkt_in, cnt_out, bkt_out, AGI, AGO);
    fused_mfma_kernel<<<NODE64_GRID, blk, 0, stream>>>(
        x, nullptr, AGI, AGO, Wr0p, in_bl0, out_bl0, cW0p, comb_b0,
        X1h, Wl1p, P, nullptr, nullptr, nullptr);

    // ---- layer 1 (+ fused final head) ----
    pull_dual_kernel<<<pull_grid, blk, 0, stream>>>(P, cnt_in, bkt_in, cnt_out, bkt_out, AGI, AGO);
    fused_mfma_kernel<<<NODE64_GRID, blk, 0, stream>>>(
        nullptr, X1h, AGI, AGO, Wr1p, in_bl1, out_bl1, cW1p, comb_b1,
        nullptr, nullptr, nullptr, final_W, final_b, out);
}